// Round 2
// baseline (421.722 us; speedup 1.0000x reference)
//
#include <hip/hip_runtime.h>

// CrissCrossAttention on MI355X. Input dtype (fp32 vs bf16) detected at
// runtime by a prelude kernel; internal compute fp32 with bf16 MFMA operands.
// B=4, C=64, CQ=8, H=W=128.

#define NE 4194304ull   // B*C*H*W elements per image tensor

typedef __attribute__((ext_vector_type(8))) short short8;
typedef __attribute__((ext_vector_type(4))) float f32x4;

#define HD __device__ __forceinline__

HD float b2f(unsigned short u) { union { unsigned int i; float f; } v; v.i = ((unsigned int)u) << 16; return v.f; }
HD unsigned short f2b(float x) {
  union { float f; unsigned int i; } v; v.f = x;
  unsigned int r = v.i + 0x7FFFu + ((v.i >> 16) & 1u);
  return (unsigned short)(r >> 16);
}

HD void up8(uint4 u, float* o) {
  o[0] = b2f((unsigned short)(u.x & 0xffff)); o[1] = b2f((unsigned short)(u.x >> 16));
  o[2] = b2f((unsigned short)(u.y & 0xffff)); o[3] = b2f((unsigned short)(u.y >> 16));
  o[4] = b2f((unsigned short)(u.z & 0xffff)); o[5] = b2f((unsigned short)(u.z >> 16));
  o[6] = b2f((unsigned short)(u.w & 0xffff)); o[7] = b2f((unsigned short)(u.w >> 16));
}

HD float dot8(const float* q, uint4 u) {
  float s;
  s  = q[0]*b2f((unsigned short)(u.x & 0xffff)) + q[1]*b2f((unsigned short)(u.x >> 16));
  s += q[2]*b2f((unsigned short)(u.y & 0xffff)) + q[3]*b2f((unsigned short)(u.y >> 16));
  s += q[4]*b2f((unsigned short)(u.z & 0xffff)) + q[5]*b2f((unsigned short)(u.z >> 16));
  s += q[6]*b2f((unsigned short)(u.w & 0xffff)) + q[7]*b2f((unsigned short)(u.w >> 16));
  return s;
}

// ---------------------------------------------------------------------------
// 0) Prelude: detect input dtype (fp32 vs bf16) and canonicalize all weight/
//    param arrays to bf16 in workspace. bf16-interp of fp32 bits produces
//    |v| > 1e3 w.h.p. (mantissa-garbage halves); true bf16 x1 ~ N(0,1).
// ---------------------------------------------------------------------------
__global__ __launch_bounds__(256) void prelude_kernel(
    const void* x1,
    const void* wqA, const void* bqA, const void* wkA, const void* bkA,
    const void* wvA, const void* bvA, const void* wqB, const void* bqB,
    const void* wkB, const void* bkB, const void* wvB, const void* bvB,
    const void* wp, const void* bp, const void* gA, const void* gB,
    const void* bng, const void* bnb,
    int* flag, unsigned short* wout)
{
  __shared__ int s;
  if (threadIdx.x == 0) s = 0;
  __syncthreads();
  const float a = fabsf(b2f(((const unsigned short*)x1)[threadIdx.x]));
  if (a > 1000.0f) atomicOr(&s, 1);
  __syncthreads();
  const int f = s;
  if (threadIdx.x == 0) *flag = f;
  const void* srcs[18] = {wqA,bqA,wkA,bkA,wvA,bvA,wqB,bqB,wkB,bkB,wvB,bvB,wp,bp,gA,gB,bng,bnb};
  const int   ns[18]   = {512,  8,512,  8,4096, 64,512,  8,512,  8,4096, 64,4096,64, 1, 1, 64, 64};
  int off = 0;
  for (int k2 = 0; k2 < 18; ++k2) {
    const void* s0 = srcs[k2];
    for (int i = threadIdx.x; i < ns[k2]; i += 256)
      wout[off + i] = f ? f2b(((const float*)s0)[i]) : ((const unsigned short*)s0)[i];
    off += ns[k2];
  }
}

// ---------------------------------------------------------------------------
// 1) QKV: per (br, b, h) row. q,k bf16 pixel-major [br][b][h][w][8];
//    v bf16 [br][b][c][h][w]. Branch A: q from x2; everything else from x1.
// ---------------------------------------------------------------------------
__global__ __launch_bounds__(256) void qkv_kernel(
    const void* __restrict__ x1v, const void* __restrict__ x2v, const int* __restrict__ flag,
    const unsigned short* __restrict__ wqA, const unsigned short* __restrict__ bqA,
    const unsigned short* __restrict__ wkA, const unsigned short* __restrict__ bkA,
    const unsigned short* __restrict__ wvA, const unsigned short* __restrict__ bvA,
    const unsigned short* __restrict__ wqB, const unsigned short* __restrict__ bqB,
    const unsigned short* __restrict__ wkB, const unsigned short* __restrict__ bkB,
    const unsigned short* __restrict__ wvB, const unsigned short* __restrict__ bvB,
    unsigned short* __restrict__ q, unsigned short* __restrict__ k,
    unsigned short* __restrict__ v)
{
  const int h = blockIdx.x, b = blockIdx.y, br = blockIdx.z;
  const int tid = threadIdx.x;
  const int f32m = *flag;
  __shared__ __align__(16) float xs[64][128];
  __shared__ __align__(16) float xq[64][128];
  const float* x1f = (const float*)x1v;
  const float* x2f = (const float*)x2v;
  const unsigned short* x1h = (const unsigned short*)x1v;
  const unsigned short* x2h = (const unsigned short*)x2v;
  for (int idx = tid; idx < 8192; idx += 256) {
    const int c = idx >> 7, w = idx & 127;
    const size_t a = ((size_t)(b*64 + c)*128 + h)*128 + w;
    xs[c][w] = f32m ? x1f[a] : b2f(x1h[a]);
    if (br == 0) xq[c][w] = f32m ? x2f[a] : b2f(x2h[a]);
  }
  __syncthreads();
  const unsigned short* wq = br ? wqB : wqA;  const unsigned short* bq = br ? bqB : bqA;
  const unsigned short* wk = br ? wkB : wkA;  const unsigned short* bk = br ? bkB : bkA;
  const unsigned short* wv = br ? wvB : wvA;  const unsigned short* bv = br ? bvB : bvA;
  const size_t pixrow = ((size_t)(br*4 + b)*128 + h)*128;

  // q (half 0) / k (half 1): one pixel per thread, 8 channels packed -> 16B store
  {
    const int half = tid >> 7, w = tid & 127;
    const float (*src)[128] = (half == 0) ? ((br == 0) ? xq : xs) : xs;
    const unsigned short* wgt  = half ? wk : wq;
    const unsigned short* bias = half ? bk : bq;
    float acc[8];
    #pragma unroll
    for (int co = 0; co < 8; ++co) acc[co] = b2f(bias[co]);
    for (int ci = 0; ci < 64; ++ci) {
      const float xv = src[ci][w];
      #pragma unroll
      for (int co = 0; co < 8; ++co) acc[co] += b2f(wgt[co*64 + ci]) * xv;
    }
    uint4 pk;
    pk.x = (unsigned int)f2b(acc[0]) | ((unsigned int)f2b(acc[1]) << 16);
    pk.y = (unsigned int)f2b(acc[2]) | ((unsigned int)f2b(acc[3]) << 16);
    pk.z = (unsigned int)f2b(acc[4]) | ((unsigned int)f2b(acc[5]) << 16);
    pk.w = (unsigned int)f2b(acc[6]) | ((unsigned int)f2b(acc[7]) << 16);
    unsigned short* dst = (half ? k : q) + (pixrow + w)*8;
    *(uint4*)dst = pk;
  }
  // v: thread tile = 8 channels x 4 w
  {
    const int cog = tid >> 5, w0 = (tid & 31) * 4;
    float acc[8][4];
    #pragma unroll
    for (int c8 = 0; c8 < 8; ++c8) {
      const float bb = b2f(bv[cog*8 + c8]);
      acc[c8][0] = bb; acc[c8][1] = bb; acc[c8][2] = bb; acc[c8][3] = bb;
    }
    for (int cb = 0; cb < 8; ++cb) {
      uint4 wrow[8];
      #pragma unroll
      for (int c8 = 0; c8 < 8; ++c8) wrow[c8] = *(const uint4*)&wv[(cog*8 + c8)*64 + cb*8];
      #pragma unroll
      for (int t = 0; t < 8; ++t) {
        const int ci = cb*8 + t;
        const float4 xv = *(const float4*)&xs[ci][w0];
        #pragma unroll
        for (int c8 = 0; c8 < 8; ++c8) {
          const float wf = b2f(((const unsigned short*)&wrow[c8])[t]);
          acc[c8][0] += wf * xv.x; acc[c8][1] += wf * xv.y;
          acc[c8][2] += wf * xv.z; acc[c8][3] += wf * xv.w;
        }
      }
    }
    #pragma unroll
    for (int c8 = 0; c8 < 8; ++c8) {
      const int c = cog*8 + c8;
      uint2 pk;
      pk.x = (unsigned int)f2b(acc[c8][0]) | ((unsigned int)f2b(acc[c8][1]) << 16);
      pk.y = (unsigned int)f2b(acc[c8][2]) | ((unsigned int)f2b(acc[c8][3]) << 16);
      unsigned short* dst = v + (((size_t)(br*4 + b)*64 + c)*128 + h)*128 + w0;
      *(uint2*)dst = pk;
    }
  }
}

// ---------------------------------------------------------------------------
// 2) v transpose: vT[z][c][w][h] = v[z][c][h][w]   (z = br*4+b)
// ---------------------------------------------------------------------------
__global__ __launch_bounds__(256) void transpose_v(
    const unsigned short* __restrict__ vStd, unsigned short* __restrict__ vT)
{
  const int tile = blockIdx.x, c = blockIdx.y, z = blockIdx.z;
  const int h0 = (tile & 3) * 32, w0 = (tile >> 2) * 32;
  const size_t base = ((size_t)z*64 + c) * 16384;
  __shared__ unsigned short T[32][33];
  const int tid = threadIdx.x;
  for (int idx = tid; idx < 1024; idx += 256) {
    const int r = idx >> 5, cc = idx & 31;
    T[r][cc] = vStd[base + (size_t)(h0 + r)*128 + (w0 + cc)];
  }
  __syncthreads();
  for (int idx = tid; idx < 1024; idx += 256) {
    const int r = idx >> 5, cc = idx & 31;
    vT[base + (size_t)(w0 + r)*128 + (h0 + cc)] = T[cc][r];
  }
}

// ---------------------------------------------------------------------------
// 3) Per-direction softmax stats (max, sumexp). dir 0 = column (masked diag),
//    dir 1 = row. z = dir*2 + br.
// ---------------------------------------------------------------------------
__global__ __launch_bounds__(256) void stats_kernel(
    const unsigned short* __restrict__ q, const unsigned short* __restrict__ k,
    float* __restrict__ mH, float* __restrict__ lH,
    float* __restrict__ mW, float* __restrict__ lW)
{
  const int X = blockIdx.x, b = blockIdx.y;
  const int br = blockIdx.z & 1, dir = blockIdx.z >> 1;
  const int tid = threadIdx.x, ih = tid & 127, half = tid >> 7;
  const size_t b4h = (size_t)(br*4 + b) * 128;
  __shared__ uint4 Ks[128];
  __shared__ float mbuf[2][128], lbuf[2][128];
  if (tid < 128) {
    const int j = tid;
    const size_t pix = (b4h + (dir ? X : j))*128 + (dir ? j : X);
    Ks[j] = *(const uint4*)(k + pix*8);
  }
  __syncthreads();
  const size_t mypix = (b4h + (dir ? X : ih))*128 + (dir ? ih : X);
  float qv[8]; up8(*(const uint4*)(q + mypix*8), qv);
  float m_r = -3.0e38f, l_r = 0.0f;
  for (int jj = 0; jj < 64; ++jj) {
    const int j = half*64 + jj;
    if (dir == 0 && j == ih) continue;   // masked diagonal
    const float s = dot8(qv, Ks[j]);
    const float mn = fmaxf(m_r, s);
    l_r = l_r * __expf(m_r - mn) + __expf(s - mn);
    m_r = mn;
  }
  mbuf[half][ih] = m_r; lbuf[half][ih] = l_r;
  __syncthreads();
  if (half == 0) {
    const float m0 = m_r, l0 = l_r, m1 = mbuf[1][ih], l1 = lbuf[1][ih];
    const float m = fmaxf(m0, m1);
    const float l = l0*__expf(m0 - m) + l1*__expf(m1 - m);
    float* mOut = dir ? mW : mH; float* lOut = dir ? lW : lH;
    mOut[mypix] = m; lOut[mypix] = l;
  }
}

// ---------------------------------------------------------------------------
// 4) PV with MFMA. Per block: recompute 128x128 score tile, joint softmax
//    (combining col+row stats), build P directly in A-fragment registers,
//    V staged in B-fragment-swizzled LDS, 32 mfma_f32_16x16x32_bf16 per wave.
//    Both directions store fp32 (o_col must be fp32: BN amplifies its
//    storage error ~300x; bf16 storage alone would inject ~0.36 absmax).
// ---------------------------------------------------------------------------
__global__ __launch_bounds__(256) void pv_kernel(
    const unsigned short* __restrict__ q, const unsigned short* __restrict__ k,
    const unsigned short* __restrict__ vStd, const unsigned short* __restrict__ vT,
    const float* __restrict__ mH, const float* __restrict__ lH,
    const float* __restrict__ mW, const float* __restrict__ lW,
    float* __restrict__ outBrF, float* __restrict__ oColF)
{
  const int X = blockIdx.x, b = blockIdx.y;
  const int br = blockIdx.z & 1, dir = blockIdx.z >> 1;
  const int tid = threadIdx.x, lane = tid & 63, w4 = tid >> 6;
  const size_t b4h = (size_t)(br*4 + b) * 128;
  __shared__ uint4 Ks[128];
  __shared__ __align__(16) char smem[34048];  // Vl (16KB) then reused as Dst (64*133*4)
  uint4* Vl = (uint4*)smem;
  float* Dst = (float*)smem;

  // phase 0: stage K pixels and B-fragment-swizzled V
  if (tid < 128) {
    const int j = tid;
    const size_t pix = (b4h + (dir ? X : j))*128 + (dir ? j : X);
    Ks[j] = *(const uint4*)(k + pix*8);
  }
  const unsigned short* vsrc = dir ? vStd : vT;
  const size_t vbase = ((size_t)(br*4 + b)*64)*16384 + (size_t)X*128;
  for (int t = tid; t < 1024; t += 256) {
    const int vl = t & 63, nb = (t >> 6) & 3, kb = t >> 8;
    const int c = nb*16 + (vl & 15), j0 = kb*32 + ((vl >> 4) << 3);
    Vl[t] = *(const uint4*)(vsrc + vbase + (size_t)c*16384 + j0);
  }
  __syncthreads();

  // phase 1: scores -> joint softmax probs, packed straight into A-frag regs
  short8 af[2][4];
  #pragma unroll
  for (int ib2 = 0; ib2 < 2; ++ib2) {
    const int ib = w4*2 + ib2;
    const int m = ib*16 + (lane & 15);
    const size_t pix = (b4h + (dir ? X : m))*128 + (dir ? m : X);
    float qv[8]; up8(*(const uint4*)(q + pix*8), qv);
    const float mh = mH[pix], lh = lH[pix], mw = mW[pix], lw = lW[pix];
    const float M = fmaxf(mh, mw);
    const float invL = 1.0f / (lh*__expf(mh - M) + lw*__expf(mw - M));
    #pragma unroll
    for (int kb = 0; kb < 4; ++kb) {
      const int jbase = kb*32 + ((lane >> 4) << 3);
      union { unsigned short u[8]; short8 s; } pk;
      #pragma unroll
      for (int jj = 0; jj < 8; ++jj) {
        const int j = jbase + jj;
        float p = 0.0f;
        if (dir || (j != m)) p = __expf(dot8(qv, Ks[j]) - M) * invL;
        pk.u[jj] = f2b(p);
      }
      af[ib2][kb] = pk.s;
    }
  }

  // phase 2: D(128m x 64c) = P * V
  f32x4 acc[2][4];
  #pragma unroll
  for (int i2 = 0; i2 < 2; ++i2)
    #pragma unroll
    for (int nb = 0; nb < 4; ++nb) acc[i2][nb] = (f32x4){0.f, 0.f, 0.f, 0.f};
  #pragma unroll
  for (int nb = 0; nb < 4; ++nb)
    #pragma unroll
    for (int kb = 0; kb < 4; ++kb) {
      const short8 bfr = *(short8*)&Vl[(kb*4 + nb)*64 + lane];
      acc[0][nb] = __builtin_amdgcn_mfma_f32_16x16x32_bf16(af[0][kb], bfr, acc[0][nb], 0, 0, 0);
      acc[1][nb] = __builtin_amdgcn_mfma_f32_16x16x32_bf16(af[1][kb], bfr, acc[1][nb], 0, 0, 0);
    }
  __syncthreads();  // done reading Vl; smem becomes Dst

  // phase 3: transpose through LDS, coalesced fp32 store [c][X][m]
  #pragma unroll
  for (int i2 = 0; i2 < 2; ++i2)
    #pragma unroll
    for (int nb = 0; nb < 4; ++nb)
      #pragma unroll
      for (int r = 0; r < 4; ++r) {
        const int mm = (w4*2 + i2)*16 + ((lane >> 4) << 2) + r;
        const int cc = nb*16 + (lane & 15);
        Dst[cc*133 + mm] = acc[i2][nb][r];
      }
  __syncthreads();
  float* dst = dir ? outBrF : oColF;
  for (int t = tid; t < 8192; t += 256) {
    const int cc = t >> 7, mm = t & 127;
    dst[vbase + (size_t)cc*16384 + mm] = Dst[cc*133 + mm];
  }
}

// ---------------------------------------------------------------------------
// 5) out_br[z][c][h][w] += oColF[z][c][w][h]  (adds the oH part, fp32)
// ---------------------------------------------------------------------------
__global__ __launch_bounds__(256) void combine_kernel(
    const float* __restrict__ oColF, float* __restrict__ outBr)
{
  const int tile = blockIdx.x, c = blockIdx.y, z = blockIdx.z;
  const int h0 = (tile & 3) * 32, w0 = (tile >> 2) * 32;
  const size_t base = ((size_t)z*64 + c) * 16384;
  __shared__ float T[32][33];
  const int tid = threadIdx.x;
  for (int idx = tid; idx < 1024; idx += 256) {
    const int r = idx >> 5, cc = idx & 31;
    T[r][cc] = oColF[base + (size_t)(w0 + r)*128 + (h0 + cc)];
  }
  __syncthreads();
  for (int idx = tid; idx < 1024; idx += 256) {
    const int r = idx >> 5, cc = idx & 31;
    const size_t off = base + (size_t)(h0 + r)*128 + (w0 + cc);
    outBr[off] += T[cc][r];
  }
}

// ---------------------------------------------------------------------------
// 6) diff -> 1x1 conv -> exact GELU -> p (fp32), plus BN partial sums
// ---------------------------------------------------------------------------
__global__ __launch_bounds__(256) void proj_kernel(
    const float* __restrict__ outA, const float* __restrict__ outB,
    const unsigned short* __restrict__ wp, const unsigned short* __restrict__ bp,
    float* __restrict__ pbuf, float* __restrict__ bnAcc)
{
  const int h = blockIdx.x, b = blockIdx.y, tid = threadIdx.x;
  __shared__ __align__(16) float diffs[64][128];
  for (int idx = tid; idx < 8192; idx += 256) {
    const int c = idx >> 7, w = idx & 127;
    const size_t off = ((size_t)(b*64 + c)*128 + h)*128 + w;
    diffs[c][w] = fabsf(outA[off] - outB[off]);
  }
  __syncthreads();
  const int cog = tid >> 5, wl = tid & 31;
  float acc[8][4];
  #pragma unroll
  for (int c8 = 0; c8 < 8; ++c8) { acc[c8][0]=0.f; acc[c8][1]=0.f; acc[c8][2]=0.f; acc[c8][3]=0.f; }
  for (int cb = 0; cb < 8; ++cb) {
    uint4 wrow[8];
    #pragma unroll
    for (int c8 = 0; c8 < 8; ++c8) wrow[c8] = *(const uint4*)&wp[(cog*8 + c8)*64 + cb*8];
    #pragma unroll
    for (int t = 0; t < 8; ++t) {
      const int ci = cb*8 + t;
      const float d0 = diffs[ci][wl],     d1 = diffs[ci][wl+32];
      const float d2 = diffs[ci][wl+64],  d3 = diffs[ci][wl+96];
      #pragma unroll
      for (int c8 = 0; c8 < 8; ++c8) {
        const float wf = b2f(((const unsigned short*)&wrow[c8])[t]);
        acc[c8][0] += wf*d0; acc[c8][1] += wf*d1; acc[c8][2] += wf*d2; acc[c8][3] += wf*d3;
      }
    }
  }
  #pragma unroll
  for (int c8 = 0; c8 < 8; ++c8) {
    const int co = cog*8 + c8;
    const float bias = b2f(bp[co]);
    const size_t pb = ((size_t)(b*64 + co)*128 + h)*128;
    float s1 = 0.f, s2 = 0.f;
    #pragma unroll
    for (int t = 0; t < 4; ++t) {
      const float x = acc[c8][t] + bias;
      const float g = 0.5f * x * (1.0f + erff(x * 0.70710678118f));
      pbuf[pb + wl + t*32] = g;
      s1 += g; s2 += g*g;
    }
    #pragma unroll
    for (int off = 16; off >= 1; off >>= 1) { s1 += __shfl_xor(s1, off); s2 += __shfl_xor(s2, off); }
    if (wl == 0) { atomicAdd(&bnAcc[co], s1); atomicAdd(&bnAcc[64 + co], s2); }
  }
}

// ---------------------------------------------------------------------------
// 7) BN finalize + residuals, 4 elems/thread, dtype-adaptive I/O
// ---------------------------------------------------------------------------
__global__ __launch_bounds__(256) void final_kernel(
    const float* __restrict__ pbuf, const float* __restrict__ outA, const float* __restrict__ outB,
    const void* __restrict__ x1v, const void* __restrict__ x2v, const int* __restrict__ flag,
    const unsigned short* __restrict__ gA, const unsigned short* __restrict__ gB,
    const unsigned short* __restrict__ bng, const unsigned short* __restrict__ bnb,
    const float* __restrict__ bnAcc, void* __restrict__ outv)
{
  const int f32m = *flag;
  const int idx = (blockIdx.x * 256 + threadIdx.x) * 4;
  const int c = (idx >> 14) & 63;
  const float invN = 1.0f / 65536.0f;
  const float s1 = bnAcc[c], s2 = bnAcc[64 + c];
  const float mean = s1 * invN;
  const float var = s2 * invN - mean*mean;
  const float scale = rsqrtf(var + 1e-5f) * b2f(bng[c]);
  const float beta = b2f(bnb[c]);
  const float ga = b2f(gA[0]), gb = b2f(gB[0]);
  const float4 p4 = *(const float4*)(pbuf + idx);
  const float4 a4 = *(const float4*)(outA + idx);
  const float4 b4 = *(const float4*)(outB + idx);
  float p[4] = {p4.x, p4.y, p4.z, p4.w};
  float a[4] = {a4.x, a4.y, a4.z, a4.w};
  float bb[4] = {b4.x, b4.y, b4.z, b4.w};
  float xa[4], xb[4];
  if (f32m) {
    const float4 t1 = *(const float4*)((const float*)x1v + idx);
    const float4 t2 = *(const float4*)((const float*)x2v + idx);
    xa[0]=t1.x; xa[1]=t1.y; xa[2]=t1.z; xa[3]=t1.w;
    xb[0]=t2.x; xb[1]=t2.y; xb[2]=t2.z; xb[3]=t2.w;
  } else {
    const uint2 x1u = *(const uint2*)((const unsigned short*)x1v + idx);
    const uint2 x2u = *(const uint2*)((const unsigned short*)x2v + idx);
    xa[0] = b2f((unsigned short)(x1u.x & 0xffff)); xa[1] = b2f((unsigned short)(x1u.x >> 16));
    xa[2] = b2f((unsigned short)(x1u.y & 0xffff)); xa[3] = b2f((unsigned short)(x1u.y >> 16));
    xb[0] = b2f((unsigned short)(x2u.x & 0xffff)); xb[1] = b2f((unsigned short)(x2u.x >> 16));
    xb[2] = b2f((unsigned short)(x2u.y & 0xffff)); xb[3] = b2f((unsigned short)(x2u.y >> 16));
  }
  float o1f[4], o2f[4];
  #pragma unroll
  for (int t = 0; t < 4; ++t) {
    const float nv = (p[t] - mean)*scale + beta;
    o1f[t] = ga*a[t] + xa[t] + nv;
    o2f[t] = gb*bb[t] + xb[t] + nv;
  }
  if (f32m) {
    float* of = (float*)outv;
    *(float4*)(of + idx)      = (float4){o1f[0], o1f[1], o1f[2], o1f[3]};
    *(float4*)(of + NE + idx) = (float4){o2f[0], o2f[1], o2f[2], o2f[3]};
  } else {
    unsigned short* oh = (unsigned short*)outv;
    uint2 u1, u2;
    u1.x = (unsigned int)f2b(o1f[0]) | ((unsigned int)f2b(o1f[1]) << 16);
    u1.y = (unsigned int)f2b(o1f[2]) | ((unsigned int)f2b(o1f[3]) << 16);
    u2.x = (unsigned int)f2b(o2f[0]) | ((unsigned int)f2b(o2f[1]) << 16);
    u2.y = (unsigned int)f2b(o2f[2]) | ((unsigned int)f2b(o2f[3]) << 16);
    *(uint2*)(oh + idx) = u1;
    *(uint2*)(oh + NE + idx) = u2;
  }
}

// ---------------------------------------------------------------------------
extern "C" void kernel_launch(void* const* d_in, const int* in_sizes, int n_in,
                              void* d_out, int out_size, void* d_ws, size_t ws_size,
                              hipStream_t stream)
{
  const void* x1  = d_in[0];
  const void* x2  = d_in[1];

  char* ws = (char*)d_ws;
  const size_t MB = 1048576ull;
  // layout (~102 MB):
  unsigned short* q     = (unsigned short*)(ws);                 // 2 MB   [2][B][H][W][8] bf16
  unsigned short* kk    = (unsigned short*)(ws + 2*MB);          // 2 MB
  float* mH             = (float*)(ws + 4*MB);                   // 512 KB [2][B][H][W]
  float* lH             = (float*)(ws + 4*MB + 512*1024);        // 512 KB
  float* mW             = (float*)(ws + 5*MB);                   // 512 KB
  float* lW             = (float*)(ws + 5*MB + 512*1024);        // 512 KB
  unsigned short* vStd  = (unsigned short*)(ws + 6*MB);          // 16 MB  [2][B][C][H][W] bf16
  unsigned short* vT    = (unsigned short*)(ws + 22*MB);         // 16 MB  [2][B][C][W][H] bf16
  float* outBr          = (float*)(ws + 38*MB);                  // 32 MB  [2][B][C][H][W] f32
  float* oColF          = (float*)(ws + 70*MB);                  // 32 MB  [2][B][C][W][H] f32
  float* pbuf           = (float*)(ws + 70*MB);                  // 16 MB, aliases oColF (dead after combine)
  float* bnAcc          = (float*)(ws + 102*MB);                 // 512 B
  int*   flag           = (int*)(ws + 102*MB + 512);             // 4 B
  unsigned short* wC    = (unsigned short*)(ws + 102*MB + 1024); // 14690 bf16 canonical params

  prelude_kernel<<<1, 256, 0, stream>>>(
      x1, d_in[2], d_in[3], d_in[4], d_in[5], d_in[6], d_in[7], d_in[8], d_in[9],
      d_in[10], d_in[11], d_in[12], d_in[13], d_in[16], d_in[17], d_in[14], d_in[15],
      d_in[18], d_in[19], flag, wC);
  hipMemsetAsync(bnAcc, 0, 128*sizeof(float), stream);
  qkv_kernel<<<dim3(128, 4, 2), 256, 0, stream>>>(
      x1, x2, flag,
      wC + 0, wC + 512, wC + 520, wC + 1032, wC + 1040, wC + 5136,        // A: wq bq wk bk wv bv
      wC + 5200, wC + 5712, wC + 5720, wC + 6232, wC + 6240, wC + 10336,  // B
      q, kk, vStd);
  transpose_v<<<dim3(16, 64, 8), 256, 0, stream>>>(vStd, vT);
  stats_kernel<<<dim3(128, 4, 4), 256, 0, stream>>>(q, kk, mH, lH, mW, lW);
  pv_kernel<<<dim3(128, 4, 4), 256, 0, stream>>>(q, kk, vStd, vT, mH, lH, mW, lW, outBr, oColF);
  combine_kernel<<<dim3(16, 64, 8), 256, 0, stream>>>(oColF, outBr);
  proj_kernel<<<dim3(128, 4), 256, 0, stream>>>(outBr, outBr + NE, wC + 10400, wC + 14496, pbuf, bnAcc);
  final_kernel<<<4096, 256, 0, stream>>>(pbuf, outBr, outBr + NE, x1, x2, flag,
                                         wC + 14560, wC + 14561, wC + 14562, wC + 14626,
                                         bnAcc, d_out);
}

// Round 3
// 330.665 us; speedup vs baseline: 1.2754x; 1.2754x over previous
//
#include <hip/hip_runtime.h>

// CrissCrossAttention on MI355X. Input dtype (fp32 vs bf16) detected at
// runtime by a prelude kernel; internal compute fp32 with bf16 MFMA operands.
// B=4, C=64, CQ=8, H=W=128.

#define NE 4194304ull   // B*C*H*W elements per image tensor

typedef __attribute__((ext_vector_type(8))) short short8;
typedef __attribute__((ext_vector_type(4))) float f32x4;

#define HD __device__ __forceinline__

HD float b2f(unsigned short u) { union { unsigned int i; float f; } v; v.i = ((unsigned int)u) << 16; return v.f; }
HD unsigned short f2b(float x) {
  union { float f; unsigned int i; } v; v.f = x;
  unsigned int r = v.i + 0x7FFFu + ((v.i >> 16) & 1u);
  return (unsigned short)(r >> 16);
}

HD void up8(uint4 u, float* o) {
  o[0] = b2f((unsigned short)(u.x & 0xffff)); o[1] = b2f((unsigned short)(u.x >> 16));
  o[2] = b2f((unsigned short)(u.y & 0xffff)); o[3] = b2f((unsigned short)(u.y >> 16));
  o[4] = b2f((unsigned short)(u.z & 0xffff)); o[5] = b2f((unsigned short)(u.z >> 16));
  o[6] = b2f((unsigned short)(u.w & 0xffff)); o[7] = b2f((unsigned short)(u.w >> 16));
}

HD float dot8(const float* q, uint4 u) {
  float s;
  s  = q[0]*b2f((unsigned short)(u.x & 0xffff)) + q[1]*b2f((unsigned short)(u.x >> 16));
  s += q[2]*b2f((unsigned short)(u.y & 0xffff)) + q[3]*b2f((unsigned short)(u.y >> 16));
  s += q[4]*b2f((unsigned short)(u.z & 0xffff)) + q[5]*b2f((unsigned short)(u.z >> 16));
  s += q[6]*b2f((unsigned short)(u.w & 0xffff)) + q[7]*b2f((unsigned short)(u.w >> 16));
  return s;
}

// Abramowitz-Stegun 7.1.26 erf approximation, |abs err| <= 1.5e-7.
HD float erf_fast(float x) {
  const float ax = fabsf(x);
  const float t = 1.0f / (1.0f + 0.3275911f * ax);
  const float poly = ((((1.061405429f*t - 1.453152027f)*t + 1.421413741f)*t
                       - 0.284496736f)*t + 0.254829592f)*t;
  const float y = 1.0f - poly * __expf(-ax*ax);
  return copysignf(y, x);
}

// ---------------------------------------------------------------------------
// 0) Prelude: detect input dtype (fp32 vs bf16) and canonicalize all weight/
//    param arrays to bf16 in workspace.
// ---------------------------------------------------------------------------
__global__ __launch_bounds__(256) void prelude_kernel(
    const void* x1,
    const void* wqA, const void* bqA, const void* wkA, const void* bkA,
    const void* wvA, const void* bvA, const void* wqB, const void* bqB,
    const void* wkB, const void* bkB, const void* wvB, const void* bvB,
    const void* wp, const void* bp, const void* gA, const void* gB,
    const void* bng, const void* bnb,
    int* flag, unsigned short* wout)
{
  __shared__ int s;
  if (threadIdx.x == 0) s = 0;
  __syncthreads();
  const float a = fabsf(b2f(((const unsigned short*)x1)[threadIdx.x]));
  if (a > 1000.0f) atomicOr(&s, 1);
  __syncthreads();
  const int f = s;
  if (threadIdx.x == 0) *flag = f;
  const void* srcs[18] = {wqA,bqA,wkA,bkA,wvA,bvA,wqB,bqB,wkB,bkB,wvB,bvB,wp,bp,gA,gB,bng,bnb};
  const int   ns[18]   = {512,  8,512,  8,4096, 64,512,  8,512,  8,4096, 64,4096,64, 1, 1, 64, 64};
  int off = 0;
  for (int k2 = 0; k2 < 18; ++k2) {
    const void* s0 = srcs[k2];
    for (int i = threadIdx.x; i < ns[k2]; i += 256)
      wout[off + i] = f ? f2b(((const float*)s0)[i]) : ((const unsigned short*)s0)[i];
    off += ns[k2];
  }
}

// ---------------------------------------------------------------------------
// 1) QKV: per (br, b, h) row. q,k bf16 pixel-major [br][b][h][w][8];
//    v bf16 [br][b][c][h][w]. Branch A: q from x2; everything else from x1.
// ---------------------------------------------------------------------------
__global__ __launch_bounds__(256) void qkv_kernel(
    const void* __restrict__ x1v, const void* __restrict__ x2v, const int* __restrict__ flag,
    const unsigned short* __restrict__ wqA, const unsigned short* __restrict__ bqA,
    const unsigned short* __restrict__ wkA, const unsigned short* __restrict__ bkA,
    const unsigned short* __restrict__ wvA, const unsigned short* __restrict__ bvA,
    const unsigned short* __restrict__ wqB, const unsigned short* __restrict__ bqB,
    const unsigned short* __restrict__ wkB, const unsigned short* __restrict__ bkB,
    const unsigned short* __restrict__ wvB, const unsigned short* __restrict__ bvB,
    unsigned short* __restrict__ q, unsigned short* __restrict__ k,
    unsigned short* __restrict__ v)
{
  const int h = blockIdx.x, b = blockIdx.y, br = blockIdx.z;
  const int tid = threadIdx.x;
  const int f32m = *flag;
  __shared__ __align__(16) float xs[64][128];
  __shared__ __align__(16) float xq[64][128];
  const float* x1f = (const float*)x1v;
  const float* x2f = (const float*)x2v;
  const unsigned short* x1h = (const unsigned short*)x1v;
  const unsigned short* x2h = (const unsigned short*)x2v;
  for (int idx = tid; idx < 8192; idx += 256) {
    const int c = idx >> 7, w = idx & 127;
    const size_t a = ((size_t)(b*64 + c)*128 + h)*128 + w;
    xs[c][w] = f32m ? x1f[a] : b2f(x1h[a]);
    if (br == 0) xq[c][w] = f32m ? x2f[a] : b2f(x2h[a]);
  }
  __syncthreads();
  const unsigned short* wq = br ? wqB : wqA;  const unsigned short* bq = br ? bqB : bqA;
  const unsigned short* wk = br ? wkB : wkA;  const unsigned short* bk = br ? bkB : bkA;
  const unsigned short* wv = br ? wvB : wvA;  const unsigned short* bv = br ? bvB : bvA;
  const size_t pixrow = ((size_t)(br*4 + b)*128 + h)*128;

  // q (half 0) / k (half 1): one pixel per thread, 8 channels packed -> 16B store
  {
    const int half = tid >> 7, w = tid & 127;
    const float (*src)[128] = (half == 0) ? ((br == 0) ? xq : xs) : xs;
    const unsigned short* wgt  = half ? wk : wq;
    const unsigned short* bias = half ? bk : bq;
    float acc[8];
    #pragma unroll
    for (int co = 0; co < 8; ++co) acc[co] = b2f(bias[co]);
    for (int ci = 0; ci < 64; ++ci) {
      const float xv = src[ci][w];
      #pragma unroll
      for (int co = 0; co < 8; ++co) acc[co] += b2f(wgt[co*64 + ci]) * xv;
    }
    uint4 pk;
    pk.x = (unsigned int)f2b(acc[0]) | ((unsigned int)f2b(acc[1]) << 16);
    pk.y = (unsigned int)f2b(acc[2]) | ((unsigned int)f2b(acc[3]) << 16);
    pk.z = (unsigned int)f2b(acc[4]) | ((unsigned int)f2b(acc[5]) << 16);
    pk.w = (unsigned int)f2b(acc[6]) | ((unsigned int)f2b(acc[7]) << 16);
    unsigned short* dst = (half ? k : q) + (pixrow + w)*8;
    *(uint4*)dst = pk;
  }
  // v: thread tile = 8 channels x 4 w
  {
    const int cog = tid >> 5, w0 = (tid & 31) * 4;
    float acc[8][4];
    #pragma unroll
    for (int c8 = 0; c8 < 8; ++c8) {
      const float bb = b2f(bv[cog*8 + c8]);
      acc[c8][0] = bb; acc[c8][1] = bb; acc[c8][2] = bb; acc[c8][3] = bb;
    }
    for (int cb = 0; cb < 8; ++cb) {
      uint4 wrow[8];
      #pragma unroll
      for (int c8 = 0; c8 < 8; ++c8) wrow[c8] = *(const uint4*)&wv[(cog*8 + c8)*64 + cb*8];
      #pragma unroll
      for (int t = 0; t < 8; ++t) {
        const int ci = cb*8 + t;
        const float4 xv = *(const float4*)&xs[ci][w0];
        #pragma unroll
        for (int c8 = 0; c8 < 8; ++c8) {
          const float wf = b2f(((const unsigned short*)&wrow[c8])[t]);
          acc[c8][0] += wf * xv.x; acc[c8][1] += wf * xv.y;
          acc[c8][2] += wf * xv.z; acc[c8][3] += wf * xv.w;
        }
      }
    }
    #pragma unroll
    for (int c8 = 0; c8 < 8; ++c8) {
      const int c = cog*8 + c8;
      uint2 pk;
      pk.x = (unsigned int)f2b(acc[c8][0]) | ((unsigned int)f2b(acc[c8][1]) << 16);
      pk.y = (unsigned int)f2b(acc[c8][2]) | ((unsigned int)f2b(acc[c8][3]) << 16);
      unsigned short* dst = v + (((size_t)(br*4 + b)*64 + c)*128 + h)*128 + w0;
      *(uint2*)dst = pk;
    }
  }
}

// ---------------------------------------------------------------------------
// 2) v transpose: vT[z][c][w][h] = v[z][c][h][w]   (z = br*4+b)
// ---------------------------------------------------------------------------
__global__ __launch_bounds__(256) void transpose_v(
    const unsigned short* __restrict__ vStd, unsigned short* __restrict__ vT)
{
  const int tile = blockIdx.x, c = blockIdx.y, z = blockIdx.z;
  const int h0 = (tile & 3) * 32, w0 = (tile >> 2) * 32;
  const size_t base = ((size_t)z*64 + c) * 16384;
  __shared__ unsigned short T[32][33];
  const int tid = threadIdx.x;
  for (int idx = tid; idx < 1024; idx += 256) {
    const int r = idx >> 5, cc = idx & 31;
    T[r][cc] = vStd[base + (size_t)(h0 + r)*128 + (w0 + cc)];
  }
  __syncthreads();
  for (int idx = tid; idx < 1024; idx += 256) {
    const int r = idx >> 5, cc = idx & 31;
    vT[base + (size_t)(w0 + r)*128 + (h0 + cc)] = T[cc][r];
  }
}

// ---------------------------------------------------------------------------
// 3) Per-direction softmax stats (max, sumexp). dir 0 = column (masked diag),
//    dir 1 = row. z = dir*2 + br.
// ---------------------------------------------------------------------------
__global__ __launch_bounds__(256) void stats_kernel(
    const unsigned short* __restrict__ q, const unsigned short* __restrict__ k,
    float* __restrict__ mH, float* __restrict__ lH,
    float* __restrict__ mW, float* __restrict__ lW)
{
  const int X = blockIdx.x, b = blockIdx.y;
  const int br = blockIdx.z & 1, dir = blockIdx.z >> 1;
  const int tid = threadIdx.x, ih = tid & 127, half = tid >> 7;
  const size_t b4h = (size_t)(br*4 + b) * 128;
  __shared__ uint4 Ks[128];
  __shared__ float mbuf[2][128], lbuf[2][128];
  if (tid < 128) {
    const int j = tid;
    const size_t pix = (b4h + (dir ? X : j))*128 + (dir ? j : X);
    Ks[j] = *(const uint4*)(k + pix*8);
  }
  __syncthreads();
  const size_t mypix = (b4h + (dir ? X : ih))*128 + (dir ? ih : X);
  float qv[8]; up8(*(const uint4*)(q + mypix*8), qv);
  float m_r = -3.0e38f, l_r = 0.0f;
  for (int jj = 0; jj < 64; ++jj) {
    const int j = half*64 + jj;
    if (dir == 0 && j == ih) continue;   // masked diagonal
    const float s = dot8(qv, Ks[j]);
    const float mn = fmaxf(m_r, s);
    l_r = l_r * __expf(m_r - mn) + __expf(s - mn);
    m_r = mn;
  }
  mbuf[half][ih] = m_r; lbuf[half][ih] = l_r;
  __syncthreads();
  if (half == 0) {
    const float m0 = m_r, l0 = l_r, m1 = mbuf[1][ih], l1 = lbuf[1][ih];
    const float m = fmaxf(m0, m1);
    const float l = l0*__expf(m0 - m) + l1*__expf(m1 - m);
    float* mOut = dir ? mW : mH; float* lOut = dir ? lW : lH;
    mOut[mypix] = m; lOut[mypix] = l;
  }
}

// ---------------------------------------------------------------------------
// 4) PV with MFMA. Per block: recompute 128x128 score tile, joint softmax
//    (combining col+row stats), build P directly in A-frag registers,
//    V staged in B-frag-swizzled LDS, 32 mfma_f32_16x16x32_bf16 per wave.
// ---------------------------------------------------------------------------
__global__ __launch_bounds__(256) void pv_kernel(
    const unsigned short* __restrict__ q, const unsigned short* __restrict__ k,
    const unsigned short* __restrict__ vStd, const unsigned short* __restrict__ vT,
    const float* __restrict__ mH, const float* __restrict__ lH,
    const float* __restrict__ mW, const float* __restrict__ lW,
    float* __restrict__ outBrF, float* __restrict__ oColF)
{
  const int X = blockIdx.x, b = blockIdx.y;
  const int br = blockIdx.z & 1, dir = blockIdx.z >> 1;
  const int tid = threadIdx.x, lane = tid & 63, w4 = tid >> 6;
  const size_t b4h = (size_t)(br*4 + b) * 128;
  __shared__ uint4 Ks[128];
  __shared__ __align__(16) char smem[34048];  // Vl (16KB) then reused as Dst (64*133*4)
  uint4* Vl = (uint4*)smem;
  float* Dst = (float*)smem;

  if (tid < 128) {
    const int j = tid;
    const size_t pix = (b4h + (dir ? X : j))*128 + (dir ? j : X);
    Ks[j] = *(const uint4*)(k + pix*8);
  }
  const unsigned short* vsrc = dir ? vStd : vT;
  const size_t vbase = ((size_t)(br*4 + b)*64)*16384 + (size_t)X*128;
  for (int t = tid; t < 1024; t += 256) {
    const int vl = t & 63, nb = (t >> 6) & 3, kb = t >> 8;
    const int c = nb*16 + (vl & 15), j0 = kb*32 + ((vl >> 4) << 3);
    Vl[t] = *(const uint4*)(vsrc + vbase + (size_t)c*16384 + j0);
  }
  __syncthreads();

  short8 af[2][4];
  #pragma unroll
  for (int ib2 = 0; ib2 < 2; ++ib2) {
    const int ib = w4*2 + ib2;
    const int m = ib*16 + (lane & 15);
    const size_t pix = (b4h + (dir ? X : m))*128 + (dir ? m : X);
    float qv[8]; up8(*(const uint4*)(q + pix*8), qv);
    const float mh = mH[pix], lh = lH[pix], mw = mW[pix], lw = lW[pix];
    const float M = fmaxf(mh, mw);
    const float invL = 1.0f / (lh*__expf(mh - M) + lw*__expf(mw - M));
    #pragma unroll
    for (int kb = 0; kb < 4; ++kb) {
      const int jbase = kb*32 + ((lane >> 4) << 3);
      union { unsigned short u[8]; short8 s; } pk;
      #pragma unroll
      for (int jj = 0; jj < 8; ++jj) {
        const int j = jbase + jj;
        float p = 0.0f;
        if (dir || (j != m)) p = __expf(dot8(qv, Ks[j]) - M) * invL;
        pk.u[jj] = f2b(p);
      }
      af[ib2][kb] = pk.s;
    }
  }

  f32x4 acc[2][4];
  #pragma unroll
  for (int i2 = 0; i2 < 2; ++i2)
    #pragma unroll
    for (int nb = 0; nb < 4; ++nb) acc[i2][nb] = (f32x4){0.f, 0.f, 0.f, 0.f};
  #pragma unroll
  for (int nb = 0; nb < 4; ++nb)
    #pragma unroll
    for (int kb = 0; kb < 4; ++kb) {
      const short8 bfr = *(short8*)&Vl[(kb*4 + nb)*64 + lane];
      acc[0][nb] = __builtin_amdgcn_mfma_f32_16x16x32_bf16(af[0][kb], bfr, acc[0][nb], 0, 0, 0);
      acc[1][nb] = __builtin_amdgcn_mfma_f32_16x16x32_bf16(af[1][kb], bfr, acc[1][nb], 0, 0, 0);
    }
  __syncthreads();

  #pragma unroll
  for (int i2 = 0; i2 < 2; ++i2)
    #pragma unroll
    for (int nb = 0; nb < 4; ++nb)
      #pragma unroll
      for (int r = 0; r < 4; ++r) {
        const int mm = (w4*2 + i2)*16 + ((lane >> 4) << 2) + r;
        const int cc = nb*16 + (lane & 15);
        Dst[cc*133 + mm] = acc[i2][nb][r];
      }
  __syncthreads();
  float* dst = dir ? outBrF : oColF;
  for (int t = tid; t < 8192; t += 256) {
    const int cc = t >> 7, mm = t & 127;
    dst[vbase + (size_t)cc*16384 + mm] = Dst[cc*133 + mm];
  }
}

// ---------------------------------------------------------------------------
// 5) out_br[z][c][h][w] += oColF[z][c][w][h]  (adds the oH part, fp32)
// ---------------------------------------------------------------------------
__global__ __launch_bounds__(256) void combine_kernel(
    const float* __restrict__ oColF, float* __restrict__ outBr)
{
  const int tile = blockIdx.x, c = blockIdx.y, z = blockIdx.z;
  const int h0 = (tile & 3) * 32, w0 = (tile >> 2) * 32;
  const size_t base = ((size_t)z*64 + c) * 16384;
  __shared__ float T[32][33];
  const int tid = threadIdx.x;
  for (int idx = tid; idx < 1024; idx += 256) {
    const int r = idx >> 5, cc = idx & 31;
    T[r][cc] = oColF[base + (size_t)(w0 + r)*128 + (h0 + cc)];
  }
  __syncthreads();
  for (int idx = tid; idx < 1024; idx += 256) {
    const int r = idx >> 5, cc = idx & 31;
    const size_t off = base + (size_t)(h0 + r)*128 + (w0 + cc);
    outBr[off] += T[cc][r];
  }
}

// ---------------------------------------------------------------------------
// 6) diff -> 1x1 conv -> fast-erf GELU -> p (fp32), BN partials to global
//    (NO atomics: 65536 atomicAdds onto 4 cache lines was ~100us of stall).
//    Grid (h, b, whalf): 1024 blocks, 16KB LDS.
// ---------------------------------------------------------------------------
__global__ __launch_bounds__(256) void proj_kernel(
    const float* __restrict__ outA, const float* __restrict__ outB,
    const unsigned short* __restrict__ wp, const unsigned short* __restrict__ bp,
    float* __restrict__ pbuf, float* __restrict__ part)
{
  const int h = blockIdx.x, b = blockIdx.y, wh = blockIdx.z, tid = threadIdx.x;
  const int blk = ((h*4 + b)*2 + wh);   // 0..1023
  __shared__ __align__(16) float diffs[64][64];
  for (int idx = tid; idx < 4096; idx += 256) {
    const int c = idx >> 6, w = idx & 63;
    const size_t off = ((size_t)(b*64 + c)*128 + h)*128 + wh*64 + w;
    diffs[c][w] = fabsf(outA[off] - outB[off]);
  }
  __syncthreads();
  const int cog = tid >> 5, wl = tid & 31;
  float acc[8][2];
  #pragma unroll
  for (int c8 = 0; c8 < 8; ++c8) { acc[c8][0] = 0.f; acc[c8][1] = 0.f; }
  for (int cb = 0; cb < 8; ++cb) {
    uint4 wrow[8];
    #pragma unroll
    for (int c8 = 0; c8 < 8; ++c8) wrow[c8] = *(const uint4*)&wp[(cog*8 + c8)*64 + cb*8];
    #pragma unroll
    for (int t = 0; t < 8; ++t) {
      const int ci = cb*8 + t;
      const float d0 = diffs[ci][wl], d1 = diffs[ci][wl + 32];
      #pragma unroll
      for (int c8 = 0; c8 < 8; ++c8) {
        const float wf = b2f(((const unsigned short*)&wrow[c8])[t]);
        acc[c8][0] += wf*d0; acc[c8][1] += wf*d1;
      }
    }
  }
  #pragma unroll
  for (int c8 = 0; c8 < 8; ++c8) {
    const int co = cog*8 + c8;
    const float bias = b2f(bp[co]);
    const size_t pb = ((size_t)(b*64 + co)*128 + h)*128 + wh*64;
    float s1 = 0.f, s2 = 0.f;
    #pragma unroll
    for (int t = 0; t < 2; ++t) {
      const float x = acc[c8][t] + bias;
      const float g = 0.5f * x * (1.0f + erf_fast(x * 0.70710678118f));
      pbuf[pb + wl + t*32] = g;
      s1 += g; s2 += g*g;
    }
    #pragma unroll
    for (int off = 16; off >= 1; off >>= 1) { s1 += __shfl_xor(s1, off); s2 += __shfl_xor(s2, off); }
    if (wl == 0) {
      part[(size_t)co*1024 + blk] = s1;
      part[(size_t)(64 + co)*1024 + blk] = s2;
    }
  }
}

// ---------------------------------------------------------------------------
// 6b) reduce per-block BN partials: bnAcc[stat] = sum_i part[stat][i]
// ---------------------------------------------------------------------------
__global__ __launch_bounds__(256) void reduce_kernel(
    const float* __restrict__ part, float* __restrict__ bnAcc)
{
  const int stat = blockIdx.x, tid = threadIdx.x;
  const float4 v = *(const float4*)(part + (size_t)stat*1024 + tid*4);
  float s = v.x + v.y + v.z + v.w;
  #pragma unroll
  for (int off = 32; off >= 1; off >>= 1) s += __shfl_xor(s, off);
  __shared__ float ws4[4];
  if ((tid & 63) == 0) ws4[tid >> 6] = s;
  __syncthreads();
  if (tid == 0) bnAcc[stat] = ws4[0] + ws4[1] + ws4[2] + ws4[3];
}

// ---------------------------------------------------------------------------
// 7) BN finalize + residuals, 4 elems/thread, dtype-adaptive I/O
// ---------------------------------------------------------------------------
__global__ __launch_bounds__(256) void final_kernel(
    const float* __restrict__ pbuf, const float* __restrict__ outA, const float* __restrict__ outB,
    const void* __restrict__ x1v, const void* __restrict__ x2v, const int* __restrict__ flag,
    const unsigned short* __restrict__ gA, const unsigned short* __restrict__ gB,
    const unsigned short* __restrict__ bng, const unsigned short* __restrict__ bnb,
    const float* __restrict__ bnAcc, void* __restrict__ outv)
{
  const int f32m = *flag;
  const int idx = (blockIdx.x * 256 + threadIdx.x) * 4;
  const int c = (idx >> 14) & 63;
  const float invN = 1.0f / 65536.0f;
  const float s1 = bnAcc[c], s2 = bnAcc[64 + c];
  const float mean = s1 * invN;
  const float var = s2 * invN - mean*mean;
  const float scale = rsqrtf(var + 1e-5f) * b2f(bng[c]);
  const float beta = b2f(bnb[c]);
  const float ga = b2f(gA[0]), gb = b2f(gB[0]);
  const float4 p4 = *(const float4*)(pbuf + idx);
  const float4 a4 = *(const float4*)(outA + idx);
  const float4 b4 = *(const float4*)(outB + idx);
  float p[4] = {p4.x, p4.y, p4.z, p4.w};
  float a[4] = {a4.x, a4.y, a4.z, a4.w};
  float bb[4] = {b4.x, b4.y, b4.z, b4.w};
  float xa[4], xb[4];
  if (f32m) {
    const float4 t1 = *(const float4*)((const float*)x1v + idx);
    const float4 t2 = *(const float4*)((const float*)x2v + idx);
    xa[0]=t1.x; xa[1]=t1.y; xa[2]=t1.z; xa[3]=t1.w;
    xb[0]=t2.x; xb[1]=t2.y; xb[2]=t2.z; xb[3]=t2.w;
  } else {
    const uint2 x1u = *(const uint2*)((const unsigned short*)x1v + idx);
    const uint2 x2u = *(const uint2*)((const unsigned short*)x2v + idx);
    xa[0] = b2f((unsigned short)(x1u.x & 0xffff)); xa[1] = b2f((unsigned short)(x1u.x >> 16));
    xa[2] = b2f((unsigned short)(x1u.y & 0xffff)); xa[3] = b2f((unsigned short)(x1u.y >> 16));
    xb[0] = b2f((unsigned short)(x2u.x & 0xffff)); xb[1] = b2f((unsigned short)(x2u.x >> 16));
    xb[2] = b2f((unsigned short)(x2u.y & 0xffff)); xb[3] = b2f((unsigned short)(x2u.y >> 16));
  }
  float o1f[4], o2f[4];
  #pragma unroll
  for (int t = 0; t < 4; ++t) {
    const float nv = (p[t] - mean)*scale + beta;
    o1f[t] = ga*a[t] + xa[t] + nv;
    o2f[t] = gb*bb[t] + xb[t] + nv;
  }
  if (f32m) {
    float* of = (float*)outv;
    *(float4*)(of + idx)      = (float4){o1f[0], o1f[1], o1f[2], o1f[3]};
    *(float4*)(of + NE + idx) = (float4){o2f[0], o2f[1], o2f[2], o2f[3]};
  } else {
    unsigned short* oh = (unsigned short*)outv;
    uint2 u1, u2;
    u1.x = (unsigned int)f2b(o1f[0]) | ((unsigned int)f2b(o1f[1]) << 16);
    u1.y = (unsigned int)f2b(o1f[2]) | ((unsigned int)f2b(o1f[3]) << 16);
    u2.x = (unsigned int)f2b(o2f[0]) | ((unsigned int)f2b(o2f[1]) << 16);
    u2.y = (unsigned int)f2b(o2f[2]) | ((unsigned int)f2b(o2f[3]) << 16);
    *(uint2*)(oh + idx) = u1;
    *(uint2*)(oh + NE + idx) = u2;
  }
}

// ---------------------------------------------------------------------------
extern "C" void kernel_launch(void* const* d_in, const int* in_sizes, int n_in,
                              void* d_out, int out_size, void* d_ws, size_t ws_size,
                              hipStream_t stream)
{
  const void* x1  = d_in[0];
  const void* x2  = d_in[1];

  char* ws = (char*)d_ws;
  const size_t MB = 1048576ull;
  // layout (~102 MB):
  unsigned short* q     = (unsigned short*)(ws);                 // 2 MB   [2][B][H][W][8] bf16
  unsigned short* kk    = (unsigned short*)(ws + 2*MB);          // 2 MB
  float* mH             = (float*)(ws + 4*MB);                   // 512 KB [2][B][H][W]
  float* lH             = (float*)(ws + 4*MB + 512*1024);        // 512 KB
  float* mW             = (float*)(ws + 5*MB);                   // 512 KB
  float* lW             = (float*)(ws + 5*MB + 512*1024);        // 512 KB
  unsigned short* vStd  = (unsigned short*)(ws + 6*MB);          // 16 MB  [2][B][C][H][W] bf16
  unsigned short* vT    = (unsigned short*)(ws + 22*MB);         // 16 MB  [2][B][C][W][H] bf16
  float* outBr          = (float*)(ws + 38*MB);                  // 32 MB  [2][B][C][H][W] f32
  float* oColF          = (float*)(ws + 70*MB);                  // 32 MB  [2][B][C][W][H] f32
  float* pbuf           = (float*)(ws + 70*MB);                  // 16 MB, aliases oColF (dead after combine)
  float* part           = (float*)(ws + 86*MB);                  // 512 KB, aliases upper oColF (dead)
  float* bnAcc          = (float*)(ws + 102*MB);                 // 512 B
  int*   flag           = (int*)(ws + 102*MB + 512);             // 4 B
  unsigned short* wC    = (unsigned short*)(ws + 102*MB + 1024); // 14690 bf16 canonical params

  prelude_kernel<<<1, 256, 0, stream>>>(
      x1, d_in[2], d_in[3], d_in[4], d_in[5], d_in[6], d_in[7], d_in[8], d_in[9],
      d_in[10], d_in[11], d_in[12], d_in[13], d_in[16], d_in[17], d_in[14], d_in[15],
      d_in[18], d_in[19], flag, wC);
  qkv_kernel<<<dim3(128, 4, 2), 256, 0, stream>>>(
      x1, x2, flag,
      wC + 0, wC + 512, wC + 520, wC + 1032, wC + 1040, wC + 5136,        // A: wq bq wk bk wv bv
      wC + 5200, wC + 5712, wC + 5720, wC + 6232, wC + 6240, wC + 10336,  // B
      q, kk, vStd);
  transpose_v<<<dim3(16, 64, 8), 256, 0, stream>>>(vStd, vT);
  stats_kernel<<<dim3(128, 4, 4), 256, 0, stream>>>(q, kk, mH, lH, mW, lW);
  pv_kernel<<<dim3(128, 4, 4), 256, 0, stream>>>(q, kk, vStd, vT, mH, lH, mW, lW, outBr, oColF);
  combine_kernel<<<dim3(16, 64, 8), 256, 0, stream>>>(oColF, outBr);
  proj_kernel<<<dim3(128, 4, 2), 256, 0, stream>>>(outBr, outBr + NE, wC + 10400, wC + 14496, pbuf, part);
  reduce_kernel<<<128, 256, 0, stream>>>(part, bnAcc);
  final_kernel<<<4096, 256, 0, stream>>>(pbuf, outBr, outBr + NE, x1, x2, flag,
                                         wC + 14560, wC + 14561, wC + 14562, wC + 14626,
                                         bnAcc, d_out);
}

// Round 4
// 299.283 us; speedup vs baseline: 1.4091x; 1.1049x over previous
//
#include <hip/hip_runtime.h>

// CrissCrossAttention on MI355X. Input dtype (fp32 vs bf16) detected at
// runtime by a prelude kernel; internal compute fp32 with bf16 MFMA operands.
// B=4, C=64, CQ=8, H=W=128.
//
// R4 changes: qkv staged in bf16 LDS (32KB, 5 blocks/CU) with 16B/lane global
// staging; stats_kernel removed (exp without max-subtraction is safe: |s|<~4),
// pv emits unnormalized exp plus per-pixel l-sums, combine normalizes.

#define NE 4194304ull   // B*C*H*W elements per image tensor

typedef __attribute__((ext_vector_type(8))) short short8;
typedef __attribute__((ext_vector_type(4))) float f32x4;

#define HD __device__ __forceinline__

HD float b2f(unsigned short u) { union { unsigned int i; float f; } v; v.i = ((unsigned int)u) << 16; return v.f; }
HD unsigned short f2b(float x) {
  union { float f; unsigned int i; } v; v.f = x;
  unsigned int r = v.i + 0x7FFFu + ((v.i >> 16) & 1u);
  return (unsigned short)(r >> 16);
}

HD void up8(uint4 u, float* o) {
  o[0] = b2f((unsigned short)(u.x & 0xffff)); o[1] = b2f((unsigned short)(u.x >> 16));
  o[2] = b2f((unsigned short)(u.y & 0xffff)); o[3] = b2f((unsigned short)(u.y >> 16));
  o[4] = b2f((unsigned short)(u.z & 0xffff)); o[5] = b2f((unsigned short)(u.z >> 16));
  o[6] = b2f((unsigned short)(u.w & 0xffff)); o[7] = b2f((unsigned short)(u.w >> 16));
}

HD float dot8(const float* q, uint4 u) {
  float s;
  s  = q[0]*b2f((unsigned short)(u.x & 0xffff)) + q[1]*b2f((unsigned short)(u.x >> 16));
  s += q[2]*b2f((unsigned short)(u.y & 0xffff)) + q[3]*b2f((unsigned short)(u.y >> 16));
  s += q[4]*b2f((unsigned short)(u.z & 0xffff)) + q[5]*b2f((unsigned short)(u.z >> 16));
  s += q[6]*b2f((unsigned short)(u.w & 0xffff)) + q[7]*b2f((unsigned short)(u.w >> 16));
  return s;
}

// Abramowitz-Stegun 7.1.26 erf approximation, |abs err| <= 1.5e-7.
HD float erf_fast(float x) {
  const float ax = fabsf(x);
  const float t = 1.0f / (1.0f + 0.3275911f * ax);
  const float poly = ((((1.061405429f*t - 1.453152027f)*t + 1.421413741f)*t
                       - 0.284496736f)*t + 0.254829592f)*t;
  const float y = 1.0f - poly * __expf(-ax*ax);
  return copysignf(y, x);
}

// ---------------------------------------------------------------------------
// 0) Prelude: detect input dtype (fp32 vs bf16) and canonicalize all weight/
//    param arrays to bf16 in workspace.
// ---------------------------------------------------------------------------
__global__ __launch_bounds__(256) void prelude_kernel(
    const void* x1,
    const void* wqA, const void* bqA, const void* wkA, const void* bkA,
    const void* wvA, const void* bvA, const void* wqB, const void* bqB,
    const void* wkB, const void* bkB, const void* wvB, const void* bvB,
    const void* wp, const void* bp, const void* gA, const void* gB,
    const void* bng, const void* bnb,
    int* flag, unsigned short* wout)
{
  __shared__ int s;
  if (threadIdx.x == 0) s = 0;
  __syncthreads();
  const float a = fabsf(b2f(((const unsigned short*)x1)[threadIdx.x]));
  if (a > 1000.0f) atomicOr(&s, 1);
  __syncthreads();
  const int f = s;
  if (threadIdx.x == 0) *flag = f;
  const void* srcs[18] = {wqA,bqA,wkA,bkA,wvA,bvA,wqB,bqB,wkB,bkB,wvB,bvB,wp,bp,gA,gB,bng,bnb};
  const int   ns[18]   = {512,  8,512,  8,4096, 64,512,  8,512,  8,4096, 64,4096,64, 1, 1, 64, 64};
  int off = 0;
  for (int k2 = 0; k2 < 18; ++k2) {
    const void* s0 = srcs[k2];
    for (int i = threadIdx.x; i < ns[k2]; i += 256)
      wout[off + i] = f ? f2b(((const float*)s0)[i]) : ((const unsigned short*)s0)[i];
    off += ns[k2];
  }
}

// ---------------------------------------------------------------------------
// 1) QKV: per (br, b, h) row. Rows staged in bf16 LDS (16KB each; 32KB block
//    total -> 5 blocks/CU vs 2 at fp32). Global staging 16B/lane.
//    q,k bf16 pixel-major [z][h][w][8]; v bf16 [z][c][h][w].
//    Branch A: q from x2; everything else from x1.
// ---------------------------------------------------------------------------
__global__ __launch_bounds__(256) void qkv_kernel(
    const void* __restrict__ x1v, const void* __restrict__ x2v, const int* __restrict__ flag,
    const unsigned short* __restrict__ wqA, const unsigned short* __restrict__ bqA,
    const unsigned short* __restrict__ wkA, const unsigned short* __restrict__ bkA,
    const unsigned short* __restrict__ wvA, const unsigned short* __restrict__ bvA,
    const unsigned short* __restrict__ wqB, const unsigned short* __restrict__ bqB,
    const unsigned short* __restrict__ wkB, const unsigned short* __restrict__ bkB,
    const unsigned short* __restrict__ wvB, const unsigned short* __restrict__ bvB,
    unsigned short* __restrict__ q, unsigned short* __restrict__ k,
    unsigned short* __restrict__ v)
{
  const int h = blockIdx.x, b = blockIdx.y, br = blockIdx.z;
  const int tid = threadIdx.x;
  const int f32m = *flag;
  __shared__ __align__(16) unsigned short xs[64][128];   // x1 row, bf16
  __shared__ __align__(16) unsigned short xq[64][128];   // x2 row (br==0 only)
  const size_t rb = (size_t)b*1048576 + (size_t)h*128;   // + c*16384 + w
  if (f32m) {
    const float* x1f = (const float*)x1v;
    const float* x2f = (const float*)x2v;
    for (int t = tid; t < 1024; t += 256) {
      const int c = t >> 4, w8 = (t & 15) * 8;
      const size_t a = rb + (size_t)c*16384 + w8;
      float4 f0 = *(const float4*)(x1f + a);
      float4 f1 = *(const float4*)(x1f + a + 4);
      uint4 u;
      u.x = (unsigned int)f2b(f0.x) | ((unsigned int)f2b(f0.y) << 16);
      u.y = (unsigned int)f2b(f0.z) | ((unsigned int)f2b(f0.w) << 16);
      u.z = (unsigned int)f2b(f1.x) | ((unsigned int)f2b(f1.y) << 16);
      u.w = (unsigned int)f2b(f1.z) | ((unsigned int)f2b(f1.w) << 16);
      *(uint4*)&xs[c][w8] = u;
      if (br == 0) {
        f0 = *(const float4*)(x2f + a);
        f1 = *(const float4*)(x2f + a + 4);
        u.x = (unsigned int)f2b(f0.x) | ((unsigned int)f2b(f0.y) << 16);
        u.y = (unsigned int)f2b(f0.z) | ((unsigned int)f2b(f0.w) << 16);
        u.z = (unsigned int)f2b(f1.x) | ((unsigned int)f2b(f1.y) << 16);
        u.w = (unsigned int)f2b(f1.z) | ((unsigned int)f2b(f1.w) << 16);
        *(uint4*)&xq[c][w8] = u;
      }
    }
  } else {
    const unsigned short* x1h = (const unsigned short*)x1v;
    const unsigned short* x2h = (const unsigned short*)x2v;
    for (int t = tid; t < 1024; t += 256) {
      const int c = t >> 4, w8 = (t & 15) * 8;
      const size_t a = rb + (size_t)c*16384 + w8;
      *(uint4*)&xs[c][w8] = *(const uint4*)(x1h + a);
      if (br == 0) *(uint4*)&xq[c][w8] = *(const uint4*)(x2h + a);
    }
  }
  __syncthreads();
  const unsigned short* wq = br ? wqB : wqA;  const unsigned short* bq = br ? bqB : bqA;
  const unsigned short* wk = br ? wkB : wkA;  const unsigned short* bk = br ? bkB : bkA;
  const unsigned short* wv = br ? wvB : wvA;  const unsigned short* bv = br ? bvB : bvA;
  const size_t pixrow = ((size_t)(br*4 + b)*128 + h)*128;

  // q (half 0) / k (half 1): one pixel per thread, 8 channels packed
  {
    const int half = tid >> 7, w = tid & 127;
    const unsigned short (*src)[128] = (half == 0) ? ((br == 0) ? xq : xs) : xs;
    const unsigned short* wgt  = half ? wk : wq;
    const unsigned short* bias = half ? bk : bq;
    float acc[8];
    #pragma unroll
    for (int co = 0; co < 8; ++co) acc[co] = b2f(bias[co]);
    for (int ci = 0; ci < 64; ++ci) {
      const float xv = b2f(src[ci][w]);
      #pragma unroll
      for (int co = 0; co < 8; ++co) acc[co] += b2f(wgt[co*64 + ci]) * xv;
    }
    uint4 pk;
    pk.x = (unsigned int)f2b(acc[0]) | ((unsigned int)f2b(acc[1]) << 16);
    pk.y = (unsigned int)f2b(acc[2]) | ((unsigned int)f2b(acc[3]) << 16);
    pk.z = (unsigned int)f2b(acc[4]) | ((unsigned int)f2b(acc[5]) << 16);
    pk.w = (unsigned int)f2b(acc[6]) | ((unsigned int)f2b(acc[7]) << 16);
    unsigned short* dst = (half ? k : q) + (pixrow + tid % 128)*8;
    *(uint4*)dst = pk;
  }
  // v: thread tile = 8 channels x 4 w
  {
    const int cog = tid >> 5, w0 = (tid & 31) * 4;
    float acc[8][4];
    #pragma unroll
    for (int c8 = 0; c8 < 8; ++c8) {
      const float bb = b2f(bv[cog*8 + c8]);
      acc[c8][0] = bb; acc[c8][1] = bb; acc[c8][2] = bb; acc[c8][3] = bb;
    }
    for (int cb = 0; cb < 8; ++cb) {
      uint4 wrow[8];
      #pragma unroll
      for (int c8 = 0; c8 < 8; ++c8) wrow[c8] = *(const uint4*)&wv[(cog*8 + c8)*64 + cb*8];
      #pragma unroll
      for (int t = 0; t < 8; ++t) {
        const int ci = cb*8 + t;
        const uint2 xu = *(const uint2*)&xs[ci][w0];
        const float xv0 = b2f((unsigned short)(xu.x & 0xffff));
        const float xv1 = b2f((unsigned short)(xu.x >> 16));
        const float xv2 = b2f((unsigned short)(xu.y & 0xffff));
        const float xv3 = b2f((unsigned short)(xu.y >> 16));
        #pragma unroll
        for (int c8 = 0; c8 < 8; ++c8) {
          const float wf = b2f(((const unsigned short*)&wrow[c8])[t]);
          acc[c8][0] += wf * xv0; acc[c8][1] += wf * xv1;
          acc[c8][2] += wf * xv2; acc[c8][3] += wf * xv3;
        }
      }
    }
    #pragma unroll
    for (int c8 = 0; c8 < 8; ++c8) {
      const int c = cog*8 + c8;
      uint2 pk;
      pk.x = (unsigned int)f2b(acc[c8][0]) | ((unsigned int)f2b(acc[c8][1]) << 16);
      pk.y = (unsigned int)f2b(acc[c8][2]) | ((unsigned int)f2b(acc[c8][3]) << 16);
      unsigned short* dst = v + (((size_t)(br*4 + b)*64 + c)*128 + h)*128 + w0;
      *(uint2*)dst = pk;
    }
  }
}

// ---------------------------------------------------------------------------
// 2) v transpose: vT[z][c][w][h] = v[z][c][h][w]   (z = br*4+b)
// ---------------------------------------------------------------------------
__global__ __launch_bounds__(256) void transpose_v(
    const unsigned short* __restrict__ vStd, unsigned short* __restrict__ vT)
{
  const int tile = blockIdx.x, c = blockIdx.y, z = blockIdx.z;
  const int h0 = (tile & 3) * 32, w0 = (tile >> 2) * 32;
  const size_t base = ((size_t)z*64 + c) * 16384;
  __shared__ unsigned short T[32][33];
  const int tid = threadIdx.x;
  for (int idx = tid; idx < 1024; idx += 256) {
    const int r = idx >> 5, cc = idx & 31;
    T[r][cc] = vStd[base + (size_t)(h0 + r)*128 + (w0 + cc)];
  }
  __syncthreads();
  for (int idx = tid; idx < 1024; idx += 256) {
    const int r = idx >> 5, cc = idx & 31;
    vT[base + (size_t)(w0 + r)*128 + (h0 + cc)] = T[cc][r];
  }
}

// ---------------------------------------------------------------------------
// 3) PV with MFMA, UNNORMALIZED exp (no max subtraction: |scores| < ~4 by
//    construction, exp stays in fp32/bf16 range). Per block: recompute
//    128x128 score tile, P=exp(s) straight into A-frag registers, plus
//    per-pixel l-sum (2 shuffles). V staged in B-frag-swizzled LDS,
//    32 mfma_f32_16x16x32_bf16 per wave. dir1 -> outBrF + lRow;
//    dir0 -> oColF + lCol (both [z][X][m] contiguous in m).
// ---------------------------------------------------------------------------
__global__ __launch_bounds__(256) void pv_kernel(
    const unsigned short* __restrict__ q, const unsigned short* __restrict__ k,
    const unsigned short* __restrict__ vStd, const unsigned short* __restrict__ vT,
    float* __restrict__ outBrF, float* __restrict__ oColF,
    float* __restrict__ lRow, float* __restrict__ lCol)
{
  const int X = blockIdx.x, b = blockIdx.y;
  const int br = blockIdx.z & 1, dir = blockIdx.z >> 1;
  const int tid = threadIdx.x, lane = tid & 63, w4 = tid >> 6;
  const int z = br*4 + b;
  const size_t b4h = (size_t)z * 128;
  __shared__ uint4 Ks[128];
  __shared__ __align__(16) char smem[34048];  // Vl (16KB) then reused as Dst (64*133*4)
  uint4* Vl = (uint4*)smem;
  float* Dst = (float*)smem;

  if (tid < 128) {
    const int j = tid;
    const size_t pix = (b4h + (dir ? X : j))*128 + (dir ? j : X);
    Ks[j] = *(const uint4*)(k + pix*8);
  }
  const unsigned short* vsrc = dir ? vStd : vT;
  const size_t vbase = ((size_t)z*64)*16384 + (size_t)X*128;
  for (int t = tid; t < 1024; t += 256) {
    const int vl = t & 63, nb = (t >> 6) & 3, kb = t >> 8;
    const int c = nb*16 + (vl & 15), j0 = kb*32 + ((vl >> 4) << 3);
    Vl[t] = *(const uint4*)(vsrc + vbase + (size_t)c*16384 + j0);
  }
  __syncthreads();

  float* lOut = dir ? lRow : lCol;
  short8 af[2][4];
  #pragma unroll
  for (int ib2 = 0; ib2 < 2; ++ib2) {
    const int ib = w4*2 + ib2;
    const int m = ib*16 + (lane & 15);
    const size_t pix = (b4h + (dir ? X : m))*128 + (dir ? m : X);
    float qv[8]; up8(*(const uint4*)(q + pix*8), qv);
    float lsum = 0.0f;
    #pragma unroll
    for (int kb = 0; kb < 4; ++kb) {
      const int jbase = kb*32 + ((lane >> 4) << 3);
      union { unsigned short u[8]; short8 s; } pk;
      #pragma unroll
      for (int jj = 0; jj < 8; ++jj) {
        const int j = jbase + jj;
        float p = 0.0f;
        if (dir || (j != m)) p = __expf(dot8(qv, Ks[j]));
        lsum += p;
        pk.u[jj] = f2b(p);
      }
      af[ib2][kb] = pk.s;
    }
    // sum the four 32-j slices (lanes differing in bits 4,5)
    lsum += __shfl_xor(lsum, 16);
    lsum += __shfl_xor(lsum, 32);
    if (lane < 16) lOut[((size_t)z*128 + X)*128 + ib*16 + lane] = lsum;
  }

  f32x4 acc[2][4];
  #pragma unroll
  for (int i2 = 0; i2 < 2; ++i2)
    #pragma unroll
    for (int nb = 0; nb < 4; ++nb) acc[i2][nb] = (f32x4){0.f, 0.f, 0.f, 0.f};
  #pragma unroll
  for (int nb = 0; nb < 4; ++nb)
    #pragma unroll
    for (int kb = 0; kb < 4; ++kb) {
      const short8 bfr = *(short8*)&Vl[(kb*4 + nb)*64 + lane];
      acc[0][nb] = __builtin_amdgcn_mfma_f32_16x16x32_bf16(af[0][kb], bfr, acc[0][nb], 0, 0, 0);
      acc[1][nb] = __builtin_amdgcn_mfma_f32_16x16x32_bf16(af[1][kb], bfr, acc[1][nb], 0, 0, 0);
    }
  __syncthreads();

  #pragma unroll
  for (int i2 = 0; i2 < 2; ++i2)
    #pragma unroll
    for (int nb = 0; nb < 4; ++nb)
      #pragma unroll
      for (int r = 0; r < 4; ++r) {
        const int mm = (w4*2 + i2)*16 + ((lane >> 4) << 2) + r;
        const int cc = nb*16 + (lane & 15);
        Dst[cc*133 + mm] = acc[i2][nb][r];
      }
  __syncthreads();
  float* dst = dir ? outBrF : oColF;
  for (int t = tid; t < 8192; t += 256) {
    const int cc = t >> 7, mm = t & 127;
    dst[vbase + (size_t)cc*16384 + mm] = Dst[cc*133 + mm];
  }
}

// ---------------------------------------------------------------------------
// 4) combine + normalize: out[z][c][h][w] =
//        (outBrU[z][c][h][w] + oColU[z][c][w][h]) / (lRow[z][h][w] + lCol[z][w][h])
//    Grid (tile16, z8, cg4); each block does 16 channels of one 32x32 tile.
// ---------------------------------------------------------------------------
__global__ __launch_bounds__(256) void combine_kernel(
    const float* __restrict__ oColU, const float* __restrict__ lRow,
    const float* __restrict__ lCol, float* __restrict__ outBr)
{
  const int tile = blockIdx.x, z = blockIdx.y, cg = blockIdx.z;
  const int h0 = (tile & 3) * 32, w0 = (tile >> 2) * 32;
  const int tid = threadIdx.x;
  __shared__ float T[32][33];
  __shared__ float inv[32][33];    // inv[h][w]
  const size_t lzb = (size_t)z * 16384;
  for (int idx = tid; idx < 1024; idx += 256) {
    const int rr = idx >> 5, hh = idx & 31;
    T[rr][hh] = lCol[lzb + (size_t)(w0 + rr)*128 + h0 + hh];
  }
  __syncthreads();
  for (int idx = tid; idx < 1024; idx += 256) {
    const int r = idx >> 5, cc = idx & 31;
    inv[r][cc] = 1.0f / (lRow[lzb + (size_t)(h0 + r)*128 + w0 + cc] + T[cc][r]);
  }
  __syncthreads();
  for (int c = cg*16; c < cg*16 + 16; ++c) {
    const size_t base = ((size_t)z*64 + c) * 16384;
    for (int idx = tid; idx < 1024; idx += 256) {
      const int rr = idx >> 5, hh = idx & 31;
      T[rr][hh] = oColU[base + (size_t)(w0 + rr)*128 + h0 + hh];
    }
    __syncthreads();
    for (int idx = tid; idx < 1024; idx += 256) {
      const int r = idx >> 5, cc = idx & 31;
      const size_t off = base + (size_t)(h0 + r)*128 + w0 + cc;
      outBr[off] = (outBr[off] + T[cc][r]) * inv[r][cc];
    }
    __syncthreads();
  }
}

// ---------------------------------------------------------------------------
// 5) diff -> 1x1 conv -> fast-erf GELU -> p (fp32), BN partials to global.
//    Grid (h, b, whalf): 1024 blocks, 16KB LDS.
// ---------------------------------------------------------------------------
__global__ __launch_bounds__(256) void proj_kernel(
    const float* __restrict__ outA, const float* __restrict__ outB,
    const unsigned short* __restrict__ wp, const unsigned short* __restrict__ bp,
    float* __restrict__ pbuf, float* __restrict__ part)
{
  const int h = blockIdx.x, b = blockIdx.y, wh = blockIdx.z, tid = threadIdx.x;
  const int blk = ((h*4 + b)*2 + wh);   // 0..1023
  __shared__ __align__(16) float diffs[64][64];
  for (int idx = tid; idx < 4096; idx += 256) {
    const int c = idx >> 6, w = idx & 63;
    const size_t off = ((size_t)(b*64 + c)*128 + h)*128 + wh*64 + w;
    diffs[c][w] = fabsf(outA[off] - outB[off]);
  }
  __syncthreads();
  const int cog = tid >> 5, wl = tid & 31;
  float acc[8][2];
  #pragma unroll
  for (int c8 = 0; c8 < 8; ++c8) { acc[c8][0] = 0.f; acc[c8][1] = 0.f; }
  for (int cb = 0; cb < 8; ++cb) {
    uint4 wrow[8];
    #pragma unroll
    for (int c8 = 0; c8 < 8; ++c8) wrow[c8] = *(const uint4*)&wp[(cog*8 + c8)*64 + cb*8];
    #pragma unroll
    for (int t = 0; t < 8; ++t) {
      const int ci = cb*8 + t;
      const float d0 = diffs[ci][wl], d1 = diffs[ci][wl + 32];
      #pragma unroll
      for (int c8 = 0; c8 < 8; ++c8) {
        const float wf = b2f(((const unsigned short*)&wrow[c8])[t]);
        acc[c8][0] += wf*d0; acc[c8][1] += wf*d1;
      }
    }
  }
  #pragma unroll
  for (int c8 = 0; c8 < 8; ++c8) {
    const int co = cog*8 + c8;
    const float bias = b2f(bp[co]);
    const size_t pb = ((size_t)(b*64 + co)*128 + h)*128 + wh*64;
    float s1 = 0.f, s2 = 0.f;
    #pragma unroll
    for (int t = 0; t < 2; ++t) {
      const float x = acc[c8][t] + bias;
      const float g = 0.5f * x * (1.0f + erf_fast(x * 0.70710678118f));
      pbuf[pb + wl + t*32] = g;
      s1 += g; s2 += g*g;
    }
    #pragma unroll
    for (int off = 16; off >= 1; off >>= 1) { s1 += __shfl_xor(s1, off); s2 += __shfl_xor(s2, off); }
    if (wl == 0) {
      part[(size_t)co*1024 + blk] = s1;
      part[(size_t)(64 + co)*1024 + blk] = s2;
    }
  }
}

// ---------------------------------------------------------------------------
// 5b) reduce per-block BN partials: bnAcc[stat] = sum_i part[stat][i]
// ---------------------------------------------------------------------------
__global__ __launch_bounds__(256) void reduce_kernel(
    const float* __restrict__ part, float* __restrict__ bnAcc)
{
  const int stat = blockIdx.x, tid = threadIdx.x;
  const float4 v = *(const float4*)(part + (size_t)stat*1024 + tid*4);
  float s = v.x + v.y + v.z + v.w;
  #pragma unroll
  for (int off = 32; off >= 1; off >>= 1) s += __shfl_xor(s, off);
  __shared__ float ws4[4];
  if ((tid & 63) == 0) ws4[tid >> 6] = s;
  __syncthreads();
  if (tid == 0) bnAcc[stat] = ws4[0] + ws4[1] + ws4[2] + ws4[3];
}

// ---------------------------------------------------------------------------
// 6) BN finalize + residuals, 4 elems/thread, dtype-adaptive I/O
// ---------------------------------------------------------------------------
__global__ __launch_bounds__(256) void final_kernel(
    const float* __restrict__ pbuf, const float* __restrict__ outA, const float* __restrict__ outB,
    const void* __restrict__ x1v, const void* __restrict__ x2v, const int* __restrict__ flag,
    const unsigned short* __restrict__ gA, const unsigned short* __restrict__ gB,
    const unsigned short* __restrict__ bng, const unsigned short* __restrict__ bnb,
    const float* __restrict__ bnAcc, void* __restrict__ outv)
{
  const int f32m = *flag;
  const int idx = (blockIdx.x * 256 + threadIdx.x) * 4;
  const int c = (idx >> 14) & 63;
  const float invN = 1.0f / 65536.0f;
  const float s1 = bnAcc[c], s2 = bnAcc[64 + c];
  const float mean = s1 * invN;
  const float var = s2 * invN - mean*mean;
  const float scale = rsqrtf(var + 1e-5f) * b2f(bng[c]);
  const float beta = b2f(bnb[c]);
  const float ga = b2f(gA[0]), gb = b2f(gB[0]);
  const float4 p4 = *(const float4*)(pbuf + idx);
  const float4 a4 = *(const float4*)(outA + idx);
  const float4 b4 = *(const float4*)(outB + idx);
  float p[4] = {p4.x, p4.y, p4.z, p4.w};
  float a[4] = {a4.x, a4.y, a4.z, a4.w};
  float bb[4] = {b4.x, b4.y, b4.z, b4.w};
  float xa[4], xb[4];
  if (f32m) {
    const float4 t1 = *(const float4*)((const float*)x1v + idx);
    const float4 t2 = *(const float4*)((const float*)x2v + idx);
    xa[0]=t1.x; xa[1]=t1.y; xa[2]=t1.z; xa[3]=t1.w;
    xb[0]=t2.x; xb[1]=t2.y; xb[2]=t2.z; xb[3]=t2.w;
  } else {
    const uint2 x1u = *(const uint2*)((const unsigned short*)x1v + idx);
    const uint2 x2u = *(const uint2*)((const unsigned short*)x2v + idx);
    xa[0] = b2f((unsigned short)(x1u.x & 0xffff)); xa[1] = b2f((unsigned short)(x1u.x >> 16));
    xa[2] = b2f((unsigned short)(x1u.y & 0xffff)); xa[3] = b2f((unsigned short)(x1u.y >> 16));
    xb[0] = b2f((unsigned short)(x2u.x & 0xffff)); xb[1] = b2f((unsigned short)(x2u.x >> 16));
    xb[2] = b2f((unsigned short)(x2u.y & 0xffff)); xb[3] = b2f((unsigned short)(x2u.y >> 16));
  }
  float o1f[4], o2f[4];
  #pragma unroll
  for (int t = 0; t < 4; ++t) {
    const float nv = (p[t] - mean)*scale + beta;
    o1f[t] = ga*a[t] + xa[t] + nv;
    o2f[t] = gb*bb[t] + xb[t] + nv;
  }
  if (f32m) {
    float* of = (float*)outv;
    *(float4*)(of + idx)      = (float4){o1f[0], o1f[1], o1f[2], o1f[3]};
    *(float4*)(of + NE + idx) = (float4){o2f[0], o2f[1], o2f[2], o2f[3]};
  } else {
    unsigned short* oh = (unsigned short*)outv;
    uint2 u1, u2;
    u1.x = (unsigned int)f2b(o1f[0]) | ((unsigned int)f2b(o1f[1]) << 16);
    u1.y = (unsigned int)f2b(o1f[2]) | ((unsigned int)f2b(o1f[3]) << 16);
    u2.x = (unsigned int)f2b(o2f[0]) | ((unsigned int)f2b(o2f[1]) << 16);
    u2.y = (unsigned int)f2b(o2f[2]) | ((unsigned int)f2b(o2f[3]) << 16);
    *(uint2*)(oh + idx) = u1;
    *(uint2*)(oh + NE + idx) = u2;
  }
}

// ---------------------------------------------------------------------------
extern "C" void kernel_launch(void* const* d_in, const int* in_sizes, int n_in,
                              void* d_out, int out_size, void* d_ws, size_t ws_size,
                              hipStream_t stream)
{
  const void* x1  = d_in[0];
  const void* x2  = d_in[1];

  char* ws = (char*)d_ws;
  const size_t MB = 1048576ull;
  // layout (~102 MB):
  unsigned short* q     = (unsigned short*)(ws);                 // 2 MB   [2][B][H][W][8] bf16
  unsigned short* kk    = (unsigned short*)(ws + 2*MB);          // 2 MB
  float* lRow           = (float*)(ws + 4*MB);                   // 512 KB [z][h][w]
  float* lCol           = (float*)(ws + 4*MB + 512*1024);        // 512 KB [z][w][h]
  unsigned short* vStd  = (unsigned short*)(ws + 6*MB);          // 16 MB  [z][C][H][W] bf16
  unsigned short* vT    = (unsigned short*)(ws + 22*MB);         // 16 MB  [z][C][W][H] bf16
  float* outBr          = (float*)(ws + 38*MB);                  // 32 MB  [z][C][H][W] f32
  float* oColF          = (float*)(ws + 70*MB);                  // 32 MB  [z][C][W][H] f32
  float* pbuf           = (float*)(ws + 70*MB);                  // 16 MB, aliases oColF (dead after combine)
  float* part           = (float*)(ws + 86*MB);                  // 512 KB, aliases upper oColF (dead)
  float* bnAcc          = (float*)(ws + 102*MB);                 // 512 B
  int*   flag           = (int*)(ws + 102*MB + 512);             // 4 B
  unsigned short* wC    = (unsigned short*)(ws + 102*MB + 1024); // 14690 bf16 canonical params

  prelude_kernel<<<1, 256, 0, stream>>>(
      x1, d_in[2], d_in[3], d_in[4], d_in[5], d_in[6], d_in[7], d_in[8], d_in[9],
      d_in[10], d_in[11], d_in[12], d_in[13], d_in[16], d_in[17], d_in[14], d_in[15],
      d_in[18], d_in[19], flag, wC);
  qkv_kernel<<<dim3(128, 4, 2), 256, 0, stream>>>(
      x1, x2, flag,
      wC + 0, wC + 512, wC + 520, wC + 1032, wC + 1040, wC + 5136,        // A: wq bq wk bk wv bv
      wC + 5200, wC + 5712, wC + 5720, wC + 6232, wC + 6240, wC + 10336,  // B
      q, kk, vStd);
  transpose_v<<<dim3(16, 64, 8), 256, 0, stream>>>(vStd, vT);
  pv_kernel<<<dim3(128, 4, 4), 256, 0, stream>>>(q, kk, vStd, vT, outBr, oColF, lRow, lCol);
  combine_kernel<<<dim3(16, 8, 4), 256, 0, stream>>>(oColF, lRow, lCol, outBr);
  proj_kernel<<<dim3(128, 4, 2), 256, 0, stream>>>(outBr, outBr + NE, wC + 10400, wC + 14496, pbuf, part);
  reduce_kernel<<<128, 256, 0, stream>>>(part, bnAcc);
  final_kernel<<<4096, 256, 0, stream>>>(pbuf, outBr, outBr + NE, x1, x2, flag,
                                         wC + 14560, wC + 14561, wC + 14562, wC + 14626,
                                         bnAcc, d_out);
}

// Round 5
// 277.019 us; speedup vs baseline: 1.5224x; 1.0804x over previous
//
#include <hip/hip_runtime.h>

// CrissCrossAttention on MI355X. Input dtype (fp32 vs bf16) detected at
// runtime by a prelude kernel; internal compute fp32 with bf16 MFMA operands.
// B=4, C=64, CQ=8, H=W=128.
//
// R5: qkv rewritten as MFMA GEMM (D[80 outch][256 pix] per (b, h-pair) block,
// B-fragments register-cached, LDS reused staging->epilogue); combine
// rewritten vectorized (float4, 8ch/block, 1024 blocks).

#define NE 4194304ull   // B*C*H*W elements per image tensor

typedef __attribute__((ext_vector_type(8))) short short8;
typedef __attribute__((ext_vector_type(4))) float f32x4;

#define HD __device__ __forceinline__

HD float b2f(unsigned short u) { union { unsigned int i; float f; } v; v.i = ((unsigned int)u) << 16; return v.f; }
HD unsigned short f2b(float x) {
  union { float f; unsigned int i; } v; v.f = x;
  unsigned int r = v.i + 0x7FFFu + ((v.i >> 16) & 1u);
  return (unsigned short)(r >> 16);
}

HD void up8(uint4 u, float* o) {
  o[0] = b2f((unsigned short)(u.x & 0xffff)); o[1] = b2f((unsigned short)(u.x >> 16));
  o[2] = b2f((unsigned short)(u.y & 0xffff)); o[3] = b2f((unsigned short)(u.y >> 16));
  o[4] = b2f((unsigned short)(u.z & 0xffff)); o[5] = b2f((unsigned short)(u.z >> 16));
  o[6] = b2f((unsigned short)(u.w & 0xffff)); o[7] = b2f((unsigned short)(u.w >> 16));
}

HD float dot8(const float* q, uint4 u) {
  float s;
  s  = q[0]*b2f((unsigned short)(u.x & 0xffff)) + q[1]*b2f((unsigned short)(u.x >> 16));
  s += q[2]*b2f((unsigned short)(u.y & 0xffff)) + q[3]*b2f((unsigned short)(u.y >> 16));
  s += q[4]*b2f((unsigned short)(u.z & 0xffff)) + q[5]*b2f((unsigned short)(u.z >> 16));
  s += q[6]*b2f((unsigned short)(u.w & 0xffff)) + q[7]*b2f((unsigned short)(u.w >> 16));
  return s;
}

// Abramowitz-Stegun 7.1.26 erf approximation, |abs err| <= 1.5e-7.
HD float erf_fast(float x) {
  const float ax = fabsf(x);
  const float t = 1.0f / (1.0f + 0.3275911f * ax);
  const float poly = ((((1.061405429f*t - 1.453152027f)*t + 1.421413741f)*t
                       - 0.284496736f)*t + 0.254829592f)*t;
  const float y = 1.0f - poly * __expf(-ax*ax);
  return copysignf(y, x);
}

// ---------------------------------------------------------------------------
// 0) Prelude: detect input dtype, canonicalize params to bf16, and build the
//    MFMA A-operand weight matrix wqkv[11 mtiles][16 rows][64 k] bf16 plus
//    bias[11][16] f32. Mtiles: 0=qA | 1=kA,qB | 2=kB | 3-6=vA | 7-10=vB.
// ---------------------------------------------------------------------------
__global__ __launch_bounds__(256) void prelude_kernel(
    const void* x1,
    const void* wqA, const void* bqA, const void* wkA, const void* bkA,
    const void* wvA, const void* bvA, const void* wqB, const void* bqB,
    const void* wkB, const void* bkB, const void* wvB, const void* bvB,
    const void* wp, const void* bp, const void* gA, const void* gB,
    const void* bng, const void* bnb,
    int* flag, unsigned short* wout)
{
  __shared__ int s;
  if (threadIdx.x == 0) s = 0;
  __syncthreads();
  const float a = fabsf(b2f(((const unsigned short*)x1)[threadIdx.x]));
  if (a > 1000.0f) atomicOr(&s, 1);
  __syncthreads();
  const int f = s;
  if (threadIdx.x == 0) *flag = f;
  const void* srcs[18] = {wqA,bqA,wkA,bkA,wvA,bvA,wqB,bqB,wkB,bkB,wvB,bvB,wp,bp,gA,gB,bng,bnb};
  const int   ns[18]   = {512,  8,512,  8,4096, 64,512,  8,512,  8,4096, 64,4096,64, 1, 1, 64, 64};
  int off = 0;
  for (int k2 = 0; k2 < 18; ++k2) {
    const void* s0 = srcs[k2];
    for (int i = threadIdx.x; i < ns[k2]; i += 256)
      wout[off + i] = f ? f2b(((const float*)s0)[i]) : ((const unsigned short*)s0)[i];
    off += ns[k2];
  }
  __syncthreads();
  // build wqkv + bias from the canonicalized wout
  unsigned short* wqkv = wout + 14696;
  float* wbias = (float*)(wout + 25960);
  for (int idx = threadIdx.x; idx < 11264; idx += 256) {
    const int mt = idx >> 10, rem = idx & 1023, r = rem >> 6, ci = rem & 63;
    int src = -1;
    if (mt == 0)      { if (r < 8) src = 0 + r*64 + ci; }
    else if (mt == 1) { src = (r < 8) ? 520 + r*64 + ci : 5200 + (r-8)*64 + ci; }
    else if (mt == 2) { if (r < 8) src = 5720 + r*64 + ci; }
    else if (mt < 7)  { src = 1040 + ((mt-3)*16 + r)*64 + ci; }
    else              { src = 6240 + ((mt-7)*16 + r)*64 + ci; }
    wqkv[idx] = (src >= 0) ? wout[src] : (unsigned short)0;
  }
  for (int idx = threadIdx.x; idx < 176; idx += 256) {
    const int mt = idx >> 4, r = idx & 15;
    int src = -1;
    if (mt == 0)      { if (r < 8) src = 512 + r; }
    else if (mt == 1) { src = (r < 8) ? 1032 + r : 5712 + (r-8); }
    else if (mt == 2) { if (r < 8) src = 6232 + r; }
    else if (mt < 7)  { src = 5136 + (mt-3)*16 + r; }
    else              { src = 10336 + (mt-7)*16 + r; }
    wbias[idx] = (src >= 0) ? b2f(wout[src]) : 0.0f;
  }
}

// ---------------------------------------------------------------------------
// 1) QKV via MFMA. Grid (hp=64, b=4). Per block: 256 pixels (2 h-rows),
//    D[row][pix] = W x X. X staged pixel-major in LDS (pad 66), B-frags
//    cached in registers (x1 pass then x2 pass reusing the same LDS), then
//    11 mtiles of 8 MFMAs each with double-buffered LDS epilogue.
// ---------------------------------------------------------------------------
__global__ __launch_bounds__(256) void qkv_kernel(
    const void* __restrict__ x1v, const void* __restrict__ x2v, const int* __restrict__ flag,
    const unsigned short* __restrict__ wqkv, const float* __restrict__ wbias,
    unsigned short* __restrict__ q, unsigned short* __restrict__ k,
    unsigned short* __restrict__ v)
{
  const int hp = blockIdx.x, b = blockIdx.y;
  const int h0 = hp*2;
  const int tid = threadIdx.x, lane = tid & 63, w4 = tid >> 6;
  const int col = lane & 15, quad = lane >> 4;
  const int f32m = *flag;
  __shared__ __align__(16) char smem[33792];   // Xb[256][66] bf16, later S0/S1
  unsigned short* Xb = (unsigned short*)smem;
  unsigned short* S0 = (unsigned short*)smem;          // 16x264 bf16 = 8448B
  unsigned short* S1 = (unsigned short*)(smem + 8448);
  const size_t gb = (size_t)b*1048576 + (size_t)h0*128;

  short8 Bc[2][8];   // [pass: 0=x1, 1=x2][ntile*2 + kstep]
  #pragma unroll
  for (int pass = 0; pass < 2; ++pass) {
    const void* xv = pass ? x2v : x1v;
    // stage: transpose [c][n] -> Xb[n][c] (pad 66)
    for (int t = tid; t < 2048; t += 256) {
      const int c = t >> 5, rem = t & 31, hh = rem >> 4, w8 = (rem & 15)*8;
      const int n = hh*128 + w8;
      const size_t a = gb + (size_t)c*16384 + (size_t)hh*128 + w8;
      unsigned short vals[8];
      if (f32m) {
        const float* xf = (const float*)xv;
        const float4 f0 = *(const float4*)(xf + a);
        const float4 f1 = *(const float4*)(xf + a + 4);
        vals[0]=f2b(f0.x); vals[1]=f2b(f0.y); vals[2]=f2b(f0.z); vals[3]=f2b(f0.w);
        vals[4]=f2b(f1.x); vals[5]=f2b(f1.y); vals[6]=f2b(f1.z); vals[7]=f2b(f1.w);
      } else {
        const uint4 u = *(const uint4*)((const unsigned short*)xv + a);
        vals[0]=(unsigned short)(u.x & 0xffff); vals[1]=(unsigned short)(u.x >> 16);
        vals[2]=(unsigned short)(u.y & 0xffff); vals[3]=(unsigned short)(u.y >> 16);
        vals[4]=(unsigned short)(u.z & 0xffff); vals[5]=(unsigned short)(u.z >> 16);
        vals[6]=(unsigned short)(u.w & 0xffff); vals[7]=(unsigned short)(u.w >> 16);
      }
      #pragma unroll
      for (int i = 0; i < 8; ++i) Xb[(n + i)*66 + c] = vals[i];
    }
    __syncthreads();
    // cache B-frags: B[k][col=pixel], k = ks*32 + quad*8 + j
    const unsigned int* U = (const unsigned int*)Xb;
    #pragma unroll
    for (int nt = 0; nt < 4; ++nt)
      #pragma unroll
      for (int ks = 0; ks < 2; ++ks) {
        const int n = w4*64 + nt*16 + col;
        const int base = n*33 + (ks*32 + quad*8)/2;
        union { unsigned int u32[4]; short8 s; } p;
        #pragma unroll
        for (int jj = 0; jj < 4; ++jj) p.u32[jj] = U[base + jj];
        Bc[pass][nt*2 + ks] = p.s;
      }
    __syncthreads();
  }

  // mtile loop: 8 MFMAs -> S (ping-pong) -> output
  #pragma unroll
  for (int mt = 0; mt < 11; ++mt) {
    f32x4 acc[4];
    #pragma unroll
    for (int nt = 0; nt < 4; ++nt) acc[nt] = (f32x4){0.f, 0.f, 0.f, 0.f};
    #pragma unroll
    for (int ks = 0; ks < 2; ++ks) {
      union { uint4 u; short8 s; } A;
      A.u = *(const uint4*)(wqkv + mt*1024 + col*64 + ks*32 + quad*8);
      #pragma unroll
      for (int nt = 0; nt < 4; ++nt)
        acc[nt] = __builtin_amdgcn_mfma_f32_16x16x32_bf16(
            A.s, (mt == 0) ? Bc[1][nt*2 + ks] : Bc[0][nt*2 + ks], acc[nt], 0, 0, 0);
    }
    float bias[4];
    #pragma unroll
    for (int r = 0; r < 4; ++r) bias[r] = wbias[mt*16 + quad*4 + r];
    unsigned short* S = (mt & 1) ? S1 : S0;
    #pragma unroll
    for (int nt = 0; nt < 4; ++nt)
      #pragma unroll
      for (int r = 0; r < 4; ++r) {
        const int row = quad*4 + r;
        const int nloc = w4*64 + nt*16 + col;
        S[row*264 + nloc] = f2b(acc[nt][r] + bias[r]);
      }
    __syncthreads();
    if (mt < 3) {
      const int nloc = tid;
      const int pixg = h0*128 + nloc;
      union { unsigned short u[8]; uint4 v4; } P;
      #pragma unroll
      for (int r = 0; r < 8; ++r) P.u[r] = S[r*264 + nloc];
      if (mt == 0) {
        *(uint4*)(q + ((size_t)b*16384 + pixg)*8) = P.v4;
      } else if (mt == 1) {
        *(uint4*)(k + ((size_t)b*16384 + pixg)*8) = P.v4;
        #pragma unroll
        for (int r = 0; r < 8; ++r) P.u[r] = S[(8 + r)*264 + nloc];
        *(uint4*)(q + ((size_t)(4 + b)*16384 + pixg)*8) = P.v4;
      } else {
        *(uint4*)(k + ((size_t)(4 + b)*16384 + pixg)*8) = P.v4;
      }
    } else {
      const int vm = (mt >= 7) ? mt - 7 : mt - 3;
      const int z  = (mt >= 7) ? 4 + b : b;
      const int cl = tid >> 4, u = tid & 15;
      const int co = vm*16 + cl;
      const uint4 a0 = *(const uint4*)&S[cl*264 + u*16];
      const uint4 a1 = *(const uint4*)&S[cl*264 + u*16 + 8];
      unsigned short* dst = v + ((size_t)(z*64 + co)*16384 + (size_t)h0*128 + u*16);
      *(uint4*)dst = a0;
      *(uint4*)(dst + 8) = a1;
    }
  }
}

// ---------------------------------------------------------------------------
// 2) v transpose: vT[z][c][w][h] = v[z][c][h][w]   (z = br*4+b)
// ---------------------------------------------------------------------------
__global__ __launch_bounds__(256) void transpose_v(
    const unsigned short* __restrict__ vStd, unsigned short* __restrict__ vT)
{
  const int tile = blockIdx.x, c = blockIdx.y, z = blockIdx.z;
  const int h0 = (tile & 3) * 32, w0 = (tile >> 2) * 32;
  const size_t base = ((size_t)z*64 + c) * 16384;
  __shared__ unsigned short T[32][33];
  const int tid = threadIdx.x;
  for (int idx = tid; idx < 1024; idx += 256) {
    const int r = idx >> 5, cc = idx & 31;
    T[r][cc] = vStd[base + (size_t)(h0 + r)*128 + (w0 + cc)];
  }
  __syncthreads();
  for (int idx = tid; idx < 1024; idx += 256) {
    const int r = idx >> 5, cc = idx & 31;
    vT[base + (size_t)(w0 + r)*128 + (h0 + cc)] = T[cc][r];
  }
}

// ---------------------------------------------------------------------------
// 3) PV with MFMA, UNNORMALIZED exp (|scores| < ~4). Emits exp-weighted sums
//    plus per-pixel l-sums; combine normalizes.
// ---------------------------------------------------------------------------
__global__ __launch_bounds__(256) void pv_kernel(
    const unsigned short* __restrict__ q, const unsigned short* __restrict__ k,
    const unsigned short* __restrict__ vStd, const unsigned short* __restrict__ vT,
    float* __restrict__ outBrF, float* __restrict__ oColF,
    float* __restrict__ lRow, float* __restrict__ lCol)
{
  const int X = blockIdx.x, b = blockIdx.y;
  const int br = blockIdx.z & 1, dir = blockIdx.z >> 1;
  const int tid = threadIdx.x, lane = tid & 63, w4 = tid >> 6;
  const int z = br*4 + b;
  const size_t b4h = (size_t)z * 128;
  __shared__ uint4 Ks[128];
  __shared__ __align__(16) char smem[34048];
  uint4* Vl = (uint4*)smem;
  float* Dst = (float*)smem;

  if (tid < 128) {
    const int j = tid;
    const size_t pix = (b4h + (dir ? X : j))*128 + (dir ? j : X);
    Ks[j] = *(const uint4*)(k + pix*8);
  }
  const unsigned short* vsrc = dir ? vStd : vT;
  const size_t vbase = ((size_t)z*64)*16384 + (size_t)X*128;
  for (int t = tid; t < 1024; t += 256) {
    const int vl = t & 63, nb = (t >> 6) & 3, kb = t >> 8;
    const int c = nb*16 + (vl & 15), j0 = kb*32 + ((vl >> 4) << 3);
    Vl[t] = *(const uint4*)(vsrc + vbase + (size_t)c*16384 + j0);
  }
  __syncthreads();

  float* lOut = dir ? lRow : lCol;
  short8 af[2][4];
  #pragma unroll
  for (int ib2 = 0; ib2 < 2; ++ib2) {
    const int ib = w4*2 + ib2;
    const int m = ib*16 + (lane & 15);
    const size_t pix = (b4h + (dir ? X : m))*128 + (dir ? m : X);
    float qv[8]; up8(*(const uint4*)(q + pix*8), qv);
    float lsum = 0.0f;
    #pragma unroll
    for (int kb = 0; kb < 4; ++kb) {
      const int jbase = kb*32 + ((lane >> 4) << 3);
      union { unsigned short u[8]; short8 s; } pk;
      #pragma unroll
      for (int jj = 0; jj < 8; ++jj) {
        const int j = jbase + jj;
        float p = 0.0f;
        if (dir || (j != m)) p = __expf(dot8(qv, Ks[j]));
        lsum += p;
        pk.u[jj] = f2b(p);
      }
      af[ib2][kb] = pk.s;
    }
    lsum += __shfl_xor(lsum, 16);
    lsum += __shfl_xor(lsum, 32);
    if (lane < 16) lOut[((size_t)z*128 + X)*128 + ib*16 + lane] = lsum;
  }

  f32x4 acc[2][4];
  #pragma unroll
  for (int i2 = 0; i2 < 2; ++i2)
    #pragma unroll
    for (int nb = 0; nb < 4; ++nb) acc[i2][nb] = (f32x4){0.f, 0.f, 0.f, 0.f};
  #pragma unroll
  for (int nb = 0; nb < 4; ++nb)
    #pragma unroll
    for (int kb = 0; kb < 4; ++kb) {
      const short8 bfr = *(short8*)&Vl[(kb*4 + nb)*64 + lane];
      acc[0][nb] = __builtin_amdgcn_mfma_f32_16x16x32_bf16(af[0][kb], bfr, acc[0][nb], 0, 0, 0);
      acc[1][nb] = __builtin_amdgcn_mfma_f32_16x16x32_bf16(af[1][kb], bfr, acc[1][nb], 0, 0, 0);
    }
  __syncthreads();

  #pragma unroll
  for (int i2 = 0; i2 < 2; ++i2)
    #pragma unroll
    for (int nb = 0; nb < 4; ++nb)
      #pragma unroll
      for (int r = 0; r < 4; ++r) {
        const int mm = (w4*2 + i2)*16 + ((lane >> 4) << 2) + r;
        const int cc = nb*16 + (lane & 15);
        Dst[cc*133 + mm] = acc[i2][nb][r];
      }
  __syncthreads();
  float* dst = dir ? outBrF : oColF;
  for (int t = tid; t < 8192; t += 256) {
    const int cc = t >> 7, mm = t & 127;
    dst[vbase + (size_t)cc*16384 + mm] = Dst[cc*133 + mm];
  }
}

// ---------------------------------------------------------------------------
// 4) combine + normalize (vectorized): out[z][c][h][w] =
//    (outBrU[z][c][h][w] + oColU[z][c][w][h]) / (lRow[z][h][w] + lCol[z][w][h])
//    Grid (tile16, z8, cg8): 8 channels per block, float4 I/O.
// ---------------------------------------------------------------------------
__global__ __launch_bounds__(256) void combine_kernel(
    const float* __restrict__ oColU, const float* __restrict__ lRow,
    const float* __restrict__ lCol, float* __restrict__ outBr)
{
  const int tile = blockIdx.x, z = blockIdx.y, cg = blockIdx.z;
  const int h0 = (tile & 3) * 32, w0 = (tile >> 2) * 32, c0 = cg*8;
  const int tid = threadIdx.x;
  __shared__ float Tl[32][33];            // lCol tile [w][h]
  __shared__ __align__(16) float inv[32][36];   // [h][w]
  __shared__ __align__(16) float T4[4][32][36]; // oCol staging [ch][w][h]
  const size_t lzb = (size_t)z * 16384;
  {
    const int w = tid >> 3, h4 = (tid & 7)*4;
    const float4 vc = *(const float4*)(lCol + lzb + (size_t)(w0 + w)*128 + h0 + h4);
    Tl[w][h4+0] = vc.x; Tl[w][h4+1] = vc.y; Tl[w][h4+2] = vc.z; Tl[w][h4+3] = vc.w;
  }
  __syncthreads();
  {
    const int h = tid >> 3, w4 = (tid & 7)*4;
    const float4 lr = *(const float4*)(lRow + lzb + (size_t)(h0 + h)*128 + w0 + w4);
    float4 iv;
    iv.x = 1.0f / (lr.x + Tl[w4+0][h]);
    iv.y = 1.0f / (lr.y + Tl[w4+1][h]);
    iv.z = 1.0f / (lr.z + Tl[w4+2][h]);
    iv.w = 1.0f / (lr.w + Tl[w4+3][h]);
    *(float4*)&inv[h][w4] = iv;
  }
  __syncthreads();
  #pragma unroll
  for (int half = 0; half < 2; ++half) {
    for (int t = tid; t < 1024; t += 256) {
      const int ch = t >> 8, rem = t & 255, w = rem >> 3, h4 = (rem & 7)*4;
      const int c = c0 + half*4 + ch;
      const float4 vc = *(const float4*)(oColU + ((size_t)(z*64 + c))*16384
                                         + (size_t)(w0 + w)*128 + h0 + h4);
      *(float4*)&T4[ch][w][h4] = vc;
    }
    __syncthreads();
    for (int t = tid; t < 1024; t += 256) {
      const int ch = t >> 8, rem = t & 255, h = rem >> 3, w4 = (rem & 7)*4;
      const int c = c0 + half*4 + ch;
      const size_t off = ((size_t)(z*64 + c))*16384 + (size_t)(h0 + h)*128 + w0 + w4;
      float4 o = *(const float4*)(outBr + off);
      const float4 iv = *(const float4*)&inv[h][w4];
      o.x = (o.x + T4[ch][w4+0][h]) * iv.x;
      o.y = (o.y + T4[ch][w4+1][h]) * iv.y;
      o.z = (o.z + T4[ch][w4+2][h]) * iv.z;
      o.w = (o.w + T4[ch][w4+3][h]) * iv.w;
      *(float4*)(outBr + off) = o;
    }
    __syncthreads();
  }
}

// ---------------------------------------------------------------------------
// 5) diff -> 1x1 conv -> fast-erf GELU -> p (fp32), BN partials to global.
// ---------------------------------------------------------------------------
__global__ __launch_bounds__(256) void proj_kernel(
    const float* __restrict__ outA, const float* __restrict__ outB,
    const unsigned short* __restrict__ wp, const unsigned short* __restrict__ bp,
    float* __restrict__ pbuf, float* __restrict__ part)
{
  const int h = blockIdx.x, b = blockIdx.y, wh = blockIdx.z, tid = threadIdx.x;
  const int blk = ((h*4 + b)*2 + wh);   // 0..1023
  __shared__ __align__(16) float diffs[64][64];
  for (int idx = tid; idx < 4096; idx += 256) {
    const int c = idx >> 6, w = idx & 63;
    const size_t off = ((size_t)(b*64 + c)*128 + h)*128 + wh*64 + w;
    diffs[c][w] = fabsf(outA[off] - outB[off]);
  }
  __syncthreads();
  const int cog = tid >> 5, wl = tid & 31;
  float acc[8][2];
  #pragma unroll
  for (int c8 = 0; c8 < 8; ++c8) { acc[c8][0] = 0.f; acc[c8][1] = 0.f; }
  for (int cb = 0; cb < 8; ++cb) {
    uint4 wrow[8];
    #pragma unroll
    for (int c8 = 0; c8 < 8; ++c8) wrow[c8] = *(const uint4*)&wp[(cog*8 + c8)*64 + cb*8];
    #pragma unroll
    for (int t = 0; t < 8; ++t) {
      const int ci = cb*8 + t;
      const float d0 = diffs[ci][wl], d1 = diffs[ci][wl + 32];
      #pragma unroll
      for (int c8 = 0; c8 < 8; ++c8) {
        const float wf = b2f(((const unsigned short*)&wrow[c8])[t]);
        acc[c8][0] += wf*d0; acc[c8][1] += wf*d1;
      }
    }
  }
  #pragma unroll
  for (int c8 = 0; c8 < 8; ++c8) {
    const int co = cog*8 + c8;
    const float bias = b2f(bp[co]);
    const size_t pb = ((size_t)(b*64 + co)*128 + h)*128 + wh*64;
    float s1 = 0.f, s2 = 0.f;
    #pragma unroll
    for (int t = 0; t < 2; ++t) {
      const float x = acc[c8][t] + bias;
      const float g = 0.5f * x * (1.0f + erf_fast(x * 0.70710678118f));
      pbuf[pb + wl + t*32] = g;
      s1 += g; s2 += g*g;
    }
    #pragma unroll
    for (int off = 16; off >= 1; off >>= 1) { s1 += __shfl_xor(s1, off); s2 += __shfl_xor(s2, off); }
    if (wl == 0) {
      part[(size_t)co*1024 + blk] = s1;
      part[(size_t)(64 + co)*1024 + blk] = s2;
    }
  }
}

// ---------------------------------------------------------------------------
// 5b) reduce per-block BN partials: bnAcc[stat] = sum_i part[stat][i]
// ---------------------------------------------------------------------------
__global__ __launch_bounds__(256) void reduce_kernel(
    const float* __restrict__ part, float* __restrict__ bnAcc)
{
  const int stat = blockIdx.x, tid = threadIdx.x;
  const float4 v = *(const float4*)(part + (size_t)stat*1024 + tid*4);
  float s = v.x + v.y + v.z + v.w;
  #pragma unroll
  for (int off = 32; off >= 1; off >>= 1) s += __shfl_xor(s, off);
  __shared__ float ws4[4];
  if ((tid & 63) == 0) ws4[tid >> 6] = s;
  __syncthreads();
  if (tid == 0) bnAcc[stat] = ws4[0] + ws4[1] + ws4[2] + ws4[3];
}

// ---------------------------------------------------------------------------
// 6) BN finalize + residuals, 4 elems/thread, dtype-adaptive I/O
// ---------------------------------------------------------------------------
__global__ __launch_bounds__(256) void final_kernel(
    const float* __restrict__ pbuf, const float* __restrict__ outA, const float* __restrict__ outB,
    const void* __restrict__ x1v, const void* __restrict__ x2v, const int* __restrict__ flag,
    const unsigned short* __restrict__ gA, const unsigned short* __restrict__ gB,
    const unsigned short* __restrict__ bng, const unsigned short* __restrict__ bnb,
    const float* __restrict__ bnAcc, void* __restrict__ outv)
{
  const int f32m = *flag;
  const int idx = (blockIdx.x * 256 + threadIdx.x) * 4;
  const int c = (idx >> 14) & 63;
  const float invN = 1.0f / 65536.0f;
  const float s1 = bnAcc[c], s2 = bnAcc[64 + c];
  const float mean = s1 * invN;
  const float var = s2 * invN - mean*mean;
  const float scale = rsqrtf(var + 1e-5f) * b2f(bng[c]);
  const float beta = b2f(bnb[c]);
  const float ga = b2f(gA[0]), gb = b2f(gB[0]);
  const float4 p4 = *(const float4*)(pbuf + idx);
  const float4 a4 = *(const float4*)(outA + idx);
  const float4 b4 = *(const float4*)(outB + idx);
  float p[4] = {p4.x, p4.y, p4.z, p4.w};
  float a[4] = {a4.x, a4.y, a4.z, a4.w};
  float bb[4] = {b4.x, b4.y, b4.z, b4.w};
  float xa[4], xb[4];
  if (f32m) {
    const float4 t1 = *(const float4*)((const float*)x1v + idx);
    const float4 t2 = *(const float4*)((const float*)x2v + idx);
    xa[0]=t1.x; xa[1]=t1.y; xa[2]=t1.z; xa[3]=t1.w;
    xb[0]=t2.x; xb[1]=t2.y; xb[2]=t2.z; xb[3]=t2.w;
  } else {
    const uint2 x1u = *(const uint2*)((const unsigned short*)x1v + idx);
    const uint2 x2u = *(const uint2*)((const unsigned short*)x2v + idx);
    xa[0] = b2f((unsigned short)(x1u.x & 0xffff)); xa[1] = b2f((unsigned short)(x1u.x >> 16));
    xa[2] = b2f((unsigned short)(x1u.y & 0xffff)); xa[3] = b2f((unsigned short)(x1u.y >> 16));
    xb[0] = b2f((unsigned short)(x2u.x & 0xffff)); xb[1] = b2f((unsigned short)(x2u.x >> 16));
    xb[2] = b2f((unsigned short)(x2u.y & 0xffff)); xb[3] = b2f((unsigned short)(x2u.y >> 16));
  }
  float o1f[4], o2f[4];
  #pragma unroll
  for (int t = 0; t < 4; ++t) {
    const float nv = (p[t] - mean)*scale + beta;
    o1f[t] = ga*a[t] + xa[t] + nv;
    o2f[t] = gb*bb[t] + xb[t] + nv;
  }
  if (f32m) {
    float* of = (float*)outv;
    *(float4*)(of + idx)      = (float4){o1f[0], o1f[1], o1f[2], o1f[3]};
    *(float4*)(of + NE + idx) = (float4){o2f[0], o2f[1], o2f[2], o2f[3]};
  } else {
    unsigned short* oh = (unsigned short*)outv;
    uint2 u1, u2;
    u1.x = (unsigned int)f2b(o1f[0]) | ((unsigned int)f2b(o1f[1]) << 16);
    u1.y = (unsigned int)f2b(o1f[2]) | ((unsigned int)f2b(o1f[3]) << 16);
    u2.x = (unsigned int)f2b(o2f[0]) | ((unsigned int)f2b(o2f[1]) << 16);
    u2.y = (unsigned int)f2b(o2f[2]) | ((unsigned int)f2b(o2f[3]) << 16);
    *(uint2*)(oh + idx) = u1;
    *(uint2*)(oh + NE + idx) = u2;
  }
}

// ---------------------------------------------------------------------------
extern "C" void kernel_launch(void* const* d_in, const int* in_sizes, int n_in,
                              void* d_out, int out_size, void* d_ws, size_t ws_size,
                              hipStream_t stream)
{
  const void* x1  = d_in[0];
  const void* x2  = d_in[1];

  char* ws = (char*)d_ws;
  const size_t MB = 1048576ull;
  unsigned short* q     = (unsigned short*)(ws);                 // 2 MB   [z][pix][8] bf16
  unsigned short* kk    = (unsigned short*)(ws + 2*MB);          // 2 MB
  float* lRow           = (float*)(ws + 4*MB);                   // 512 KB [z][h][w]
  float* lCol           = (float*)(ws + 4*MB + 512*1024);        // 512 KB [z][w][h]
  unsigned short* vStd  = (unsigned short*)(ws + 6*MB);          // 16 MB  [z][C][H][W] bf16
  unsigned short* vT    = (unsigned short*)(ws + 22*MB);         // 16 MB  [z][C][W][H] bf16
  float* outBr          = (float*)(ws + 38*MB);                  // 32 MB  [z][C][H][W] f32
  float* oColF          = (float*)(ws + 70*MB);                  // 32 MB  [z][C][W][H] f32
  float* pbuf           = (float*)(ws + 70*MB);                  // 16 MB, aliases oColF
  float* part           = (float*)(ws + 86*MB);                  // 512 KB, aliases upper oColF
  float* bnAcc          = (float*)(ws + 102*MB);                 // 512 B
  int*   flag           = (int*)(ws + 102*MB + 512);             // 4 B
  unsigned short* wC    = (unsigned short*)(ws + 102*MB + 1024); // canonical params + wqkv + bias

  prelude_kernel<<<1, 256, 0, stream>>>(
      x1, d_in[2], d_in[3], d_in[4], d_in[5], d_in[6], d_in[7], d_in[8], d_in[9],
      d_in[10], d_in[11], d_in[12], d_in[13], d_in[16], d_in[17], d_in[14], d_in[15],
      d_in[18], d_in[19], flag, wC);
  qkv_kernel<<<dim3(64, 4), 256, 0, stream>>>(
      x1, x2, flag, wC + 14696, (const float*)(wC + 25960), q, kk, vStd);
  transpose_v<<<dim3(16, 64, 8), 256, 0, stream>>>(vStd, vT);
  pv_kernel<<<dim3(128, 4, 4), 256, 0, stream>>>(q, kk, vStd, vT, outBr, oColF, lRow, lCol);
  combine_kernel<<<dim3(16, 8, 8), 256, 0, stream>>>(oColF, lRow, lCol, outBr);
  proj_kernel<<<dim3(128, 4, 2), 256, 0, stream>>>(outBr, outBr + NE, wC + 10400, wC + 14496, pbuf, part);
  reduce_kernel<<<128, 256, 0, stream>>>(part, bnAcc);
  final_kernel<<<4096, 256, 0, stream>>>(pbuf, outBr, outBr + NE, x1, x2, flag,
                                         wC + 14560, wC + 14561, wC + 14562, wC + 14626,
                                         bnAcc, d_out);
}

// Round 6
// 243.384 us; speedup vs baseline: 1.7327x; 1.1382x over previous
//
#include <hip/hip_runtime.h>

// CrissCrossAttention on MI355X. Input dtype (fp32 vs bf16) detected at
// runtime; internal compute fp32 with bf16 MFMA operands.
// B=4, C=64, CQ=8, H=W=128.
//
// R6: prelude parallelized to 64 blocks (was single-block, 49us of serial
// latency). wqkv/wbias now built directly from source arrays (no dependency
// on the canonicalized wout), flag recomputed redundantly per block.

#define NE 4194304ull   // B*C*H*W elements per image tensor

typedef __attribute__((ext_vector_type(8))) short short8;
typedef __attribute__((ext_vector_type(4))) float f32x4;

#define HD __device__ __forceinline__

HD float b2f(unsigned short u) { union { unsigned int i; float f; } v; v.i = ((unsigned int)u) << 16; return v.f; }
HD unsigned short f2b(float x) {
  union { float f; unsigned int i; } v; v.f = x;
  unsigned int r = v.i + 0x7FFFu + ((v.i >> 16) & 1u);
  return (unsigned short)(r >> 16);
}

HD void up8(uint4 u, float* o) {
  o[0] = b2f((unsigned short)(u.x & 0xffff)); o[1] = b2f((unsigned short)(u.x >> 16));
  o[2] = b2f((unsigned short)(u.y & 0xffff)); o[3] = b2f((unsigned short)(u.y >> 16));
  o[4] = b2f((unsigned short)(u.z & 0xffff)); o[5] = b2f((unsigned short)(u.z >> 16));
  o[6] = b2f((unsigned short)(u.w & 0xffff)); o[7] = b2f((unsigned short)(u.w >> 16));
}

HD float dot8(const float* q, uint4 u) {
  float s;
  s  = q[0]*b2f((unsigned short)(u.x & 0xffff)) + q[1]*b2f((unsigned short)(u.x >> 16));
  s += q[2]*b2f((unsigned short)(u.y & 0xffff)) + q[3]*b2f((unsigned short)(u.y >> 16));
  s += q[4]*b2f((unsigned short)(u.z & 0xffff)) + q[5]*b2f((unsigned short)(u.z >> 16));
  s += q[6]*b2f((unsigned short)(u.w & 0xffff)) + q[7]*b2f((unsigned short)(u.w >> 16));
  return s;
}

// Abramowitz-Stegun 7.1.26 erf approximation, |abs err| <= 1.5e-7.
HD float erf_fast(float x) {
  const float ax = fabsf(x);
  const float t = 1.0f / (1.0f + 0.3275911f * ax);
  const float poly = ((((1.061405429f*t - 1.453152027f)*t + 1.421413741f)*t
                       - 0.284496736f)*t + 0.254829592f)*t;
  const float y = 1.0f - poly * __expf(-ax*ax);
  return copysignf(y, x);
}

// read element i of src as bf16, canonicalizing from fp32 if f!=0
HD unsigned short ldbf(const void* s0, int i, int f) {
  return f ? f2b(((const float*)s0)[i]) : ((const unsigned short*)s0)[i];
}

// ---------------------------------------------------------------------------
// 0) Prelude (64 blocks): detect dtype (redundantly per block), canonicalize
//    params to bf16 wout, build wqkv[11][16][64] bf16 + wbias[11][16] f32
//    directly from sources. Mtiles: 0=qA | 1=kA,qB | 2=kB | 3-6=vA | 7-10=vB.
// ---------------------------------------------------------------------------
__global__ __launch_bounds__(256) void prelude_kernel(
    const void* x1,
    const void* wqA, const void* bqA, const void* wkA, const void* bkA,
    const void* wvA, const void* bvA, const void* wqB, const void* bqB,
    const void* wkB, const void* bkB, const void* wvB, const void* bvB,
    const void* wp, const void* bp, const void* gA, const void* gB,
    const void* bng, const void* bnb,
    int* flag, unsigned short* wout)
{
  __shared__ int s;
  if (threadIdx.x == 0) s = 0;
  __syncthreads();
  const float a = fabsf(b2f(((const unsigned short*)x1)[threadIdx.x]));
  if (a > 1000.0f) atomicOr(&s, 1);
  __syncthreads();
  const int f = s;
  if (blockIdx.x == 0 && threadIdx.x == 0) *flag = f;

  const void* srcs[18] = {wqA,bqA,wkA,bkA,wvA,bvA,wqB,bqB,wkB,bkB,wvB,bvB,wp,bp,gA,gB,bng,bnb};
  const int   ns[18]   = {512,  8,512,  8,4096, 64,512,  8,512,  8,4096, 64,4096,64, 1, 1, 64, 64};
  unsigned short* wqkv = wout + 14696;
  float* wbias = (float*)(wout + 25960);

  // 26136 items: [0,14690) wout copy | [14696,25960) wqkv | [25960,26136) wbias
  const int gstride = gridDim.x * 256;
  for (int idx = blockIdx.x*256 + threadIdx.x; idx < 26136; idx += gstride) {
    if (idx < 14690) {
      int off = idx, k2 = 0;
      while (off >= ns[k2]) { off -= ns[k2]; ++k2; }
      wout[idx] = ldbf(srcs[k2], off, f);
    } else if (idx >= 25960) {
      const int i3 = idx - 25960, mt = i3 >> 4, r = i3 & 15;
      float val = 0.0f;
      if (mt == 0)      { if (r < 8) val = b2f(ldbf(bqA, r, f)); }
      else if (mt == 1) { val = b2f((r < 8) ? ldbf(bkA, r, f) : ldbf(bqB, r - 8, f)); }
      else if (mt == 2) { if (r < 8) val = b2f(ldbf(bkB, r, f)); }
      else if (mt < 7)  { val = b2f(ldbf(bvA, (mt-3)*16 + r, f)); }
      else              { val = b2f(ldbf(bvB, (mt-7)*16 + r, f)); }
      wbias[i3] = val;
    } else if (idx >= 14696) {
      const int i2 = idx - 14696;
      const int mt = i2 >> 10, rem = i2 & 1023, r = rem >> 6, ci = rem & 63;
      unsigned short val = 0;
      if (mt == 0)      { if (r < 8) val = ldbf(wqA, r*64 + ci, f); }
      else if (mt == 1) { val = (r < 8) ? ldbf(wkA, r*64 + ci, f) : ldbf(wqB, (r-8)*64 + ci, f); }
      else if (mt == 2) { if (r < 8) val = ldbf(wkB, r*64 + ci, f); }
      else if (mt < 7)  { val = ldbf(wvA, ((mt-3)*16 + r)*64 + ci, f); }
      else              { val = ldbf(wvB, ((mt-7)*16 + r)*64 + ci, f); }
      wqkv[i2] = val;
    }
  }
}

// ---------------------------------------------------------------------------
// 1) QKV via MFMA. Grid (hp=64, b=4). Per block: 256 pixels (2 h-rows),
//    D[row][pix] = W x X. X staged pixel-major in LDS (pad 66), B-frags
//    cached in registers (x1 pass then x2 pass reusing the same LDS), then
//    11 mtiles of 8 MFMAs each with double-buffered LDS epilogue.
// ---------------------------------------------------------------------------
__global__ __launch_bounds__(256) void qkv_kernel(
    const void* __restrict__ x1v, const void* __restrict__ x2v, const int* __restrict__ flag,
    const unsigned short* __restrict__ wqkv, const float* __restrict__ wbias,
    unsigned short* __restrict__ q, unsigned short* __restrict__ k,
    unsigned short* __restrict__ v)
{
  const int hp = blockIdx.x, b = blockIdx.y;
  const int h0 = hp*2;
  const int tid = threadIdx.x, lane = tid & 63, w4 = tid >> 6;
  const int col = lane & 15, quad = lane >> 4;
  const int f32m = *flag;
  __shared__ __align__(16) char smem[33792];   // Xb[256][66] bf16, later S0/S1
  unsigned short* Xb = (unsigned short*)smem;
  unsigned short* S0 = (unsigned short*)smem;          // 16x264 bf16 = 8448B
  unsigned short* S1 = (unsigned short*)(smem + 8448);
  const size_t gb = (size_t)b*1048576 + (size_t)h0*128;

  short8 Bc[2][8];   // [pass: 0=x1, 1=x2][ntile*2 + kstep]
  #pragma unroll
  for (int pass = 0; pass < 2; ++pass) {
    const void* xv = pass ? x2v : x1v;
    for (int t = tid; t < 2048; t += 256) {
      const int c = t >> 5, rem = t & 31, hh = rem >> 4, w8 = (rem & 15)*8;
      const int n = hh*128 + w8;
      const size_t a = gb + (size_t)c*16384 + (size_t)hh*128 + w8;
      unsigned short vals[8];
      if (f32m) {
        const float* xf = (const float*)xv;
        const float4 f0 = *(const float4*)(xf + a);
        const float4 f1 = *(const float4*)(xf + a + 4);
        vals[0]=f2b(f0.x); vals[1]=f2b(f0.y); vals[2]=f2b(f0.z); vals[3]=f2b(f0.w);
        vals[4]=f2b(f1.x); vals[5]=f2b(f1.y); vals[6]=f2b(f1.z); vals[7]=f2b(f1.w);
      } else {
        const uint4 u = *(const uint4*)((const unsigned short*)xv + a);
        vals[0]=(unsigned short)(u.x & 0xffff); vals[1]=(unsigned short)(u.x >> 16);
        vals[2]=(unsigned short)(u.y & 0xffff); vals[3]=(unsigned short)(u.y >> 16);
        vals[4]=(unsigned short)(u.z & 0xffff); vals[5]=(unsigned short)(u.z >> 16);
        vals[6]=(unsigned short)(u.w & 0xffff); vals[7]=(unsigned short)(u.w >> 16);
      }
      #pragma unroll
      for (int i = 0; i < 8; ++i) Xb[(n + i)*66 + c] = vals[i];
    }
    __syncthreads();
    const unsigned int* U = (const unsigned int*)Xb;
    #pragma unroll
    for (int nt = 0; nt < 4; ++nt)
      #pragma unroll
      for (int ks = 0; ks < 2; ++ks) {
        const int n = w4*64 + nt*16 + col;
        const int base = n*33 + (ks*32 + quad*8)/2;
        union { unsigned int u32[4]; short8 s; } p;
        #pragma unroll
        for (int jj = 0; jj < 4; ++jj) p.u32[jj] = U[base + jj];
        Bc[pass][nt*2 + ks] = p.s;
      }
    __syncthreads();
  }

  #pragma unroll
  for (int mt = 0; mt < 11; ++mt) {
    f32x4 acc[4];
    #pragma unroll
    for (int nt = 0; nt < 4; ++nt) acc[nt] = (f32x4){0.f, 0.f, 0.f, 0.f};
    #pragma unroll
    for (int ks = 0; ks < 2; ++ks) {
      union { uint4 u; short8 s; } A;
      A.u = *(const uint4*)(wqkv + mt*1024 + col*64 + ks*32 + quad*8);
      #pragma unroll
      for (int nt = 0; nt < 4; ++nt)
        acc[nt] = __builtin_amdgcn_mfma_f32_16x16x32_bf16(
            A.s, (mt == 0) ? Bc[1][nt*2 + ks] : Bc[0][nt*2 + ks], acc[nt], 0, 0, 0);
    }
    float bias[4];
    #pragma unroll
    for (int r = 0; r < 4; ++r) bias[r] = wbias[mt*16 + quad*4 + r];
    unsigned short* S = (mt & 1) ? S1 : S0;
    #pragma unroll
    for (int nt = 0; nt < 4; ++nt)
      #pragma unroll
      for (int r = 0; r < 4; ++r) {
        const int row = quad*4 + r;
        const int nloc = w4*64 + nt*16 + col;
        S[row*264 + nloc] = f2b(acc[nt][r] + bias[r]);
      }
    __syncthreads();
    if (mt < 3) {
      const int nloc = tid;
      const int pixg = h0*128 + nloc;
      union { unsigned short u[8]; uint4 v4; } P;
      #pragma unroll
      for (int r = 0; r < 8; ++r) P.u[r] = S[r*264 + nloc];
      if (mt == 0) {
        *(uint4*)(q + ((size_t)b*16384 + pixg)*8) = P.v4;
      } else if (mt == 1) {
        *(uint4*)(k + ((size_t)b*16384 + pixg)*8) = P.v4;
        #pragma unroll
        for (int r = 0; r < 8; ++r) P.u[r] = S[(8 + r)*264 + nloc];
        *(uint4*)(q + ((size_t)(4 + b)*16384 + pixg)*8) = P.v4;
      } else {
        *(uint4*)(k + ((size_t)(4 + b)*16384 + pixg)*8) = P.v4;
      }
    } else {
      const int vm = (mt >= 7) ? mt - 7 : mt - 3;
      const int z  = (mt >= 7) ? 4 + b : b;
      const int cl = tid >> 4, u = tid & 15;
      const int co = vm*16 + cl;
      const uint4 a0 = *(const uint4*)&S[cl*264 + u*16];
      const uint4 a1 = *(const uint4*)&S[cl*264 + u*16 + 8];
      unsigned short* dst = v + ((size_t)(z*64 + co)*16384 + (size_t)h0*128 + u*16);
      *(uint4*)dst = a0;
      *(uint4*)(dst + 8) = a1;
    }
  }
}

// ---------------------------------------------------------------------------
// 2) v transpose: vT[z][c][w][h] = v[z][c][h][w]   (z = br*4+b)
// ---------------------------------------------------------------------------
__global__ __launch_bounds__(256) void transpose_v(
    const unsigned short* __restrict__ vStd, unsigned short* __restrict__ vT)
{
  const int tile = blockIdx.x, c = blockIdx.y, z = blockIdx.z;
  const int h0 = (tile & 3) * 32, w0 = (tile >> 2) * 32;
  const size_t base = ((size_t)z*64 + c) * 16384;
  __shared__ unsigned short T[32][33];
  const int tid = threadIdx.x;
  for (int idx = tid; idx < 1024; idx += 256) {
    const int r = idx >> 5, cc = idx & 31;
    T[r][cc] = vStd[base + (size_t)(h0 + r)*128 + (w0 + cc)];
  }
  __syncthreads();
  for (int idx = tid; idx < 1024; idx += 256) {
    const int r = idx >> 5, cc = idx & 31;
    vT[base + (size_t)(w0 + r)*128 + (h0 + cc)] = T[cc][r];
  }
}

// ---------------------------------------------------------------------------
// 3) PV with MFMA, UNNORMALIZED exp (|scores| < ~4). Emits exp-weighted sums
//    plus per-pixel l-sums; combine normalizes.
// ---------------------------------------------------------------------------
__global__ __launch_bounds__(256) void pv_kernel(
    const unsigned short* __restrict__ q, const unsigned short* __restrict__ k,
    const unsigned short* __restrict__ vStd, const unsigned short* __restrict__ vT,
    float* __restrict__ outBrF, float* __restrict__ oColF,
    float* __restrict__ lRow, float* __restrict__ lCol)
{
  const int X = blockIdx.x, b = blockIdx.y;
  const int br = blockIdx.z & 1, dir = blockIdx.z >> 1;
  const int tid = threadIdx.x, lane = tid & 63, w4 = tid >> 6;
  const int z = br*4 + b;
  const size_t b4h = (size_t)z * 128;
  __shared__ uint4 Ks[128];
  __shared__ __align__(16) char smem[34048];
  uint4* Vl = (uint4*)smem;
  float* Dst = (float*)smem;

  if (tid < 128) {
    const int j = tid;
    const size_t pix = (b4h + (dir ? X : j))*128 + (dir ? j : X);
    Ks[j] = *(const uint4*)(k + pix*8);
  }
  const unsigned short* vsrc = dir ? vStd : vT;
  const size_t vbase = ((size_t)z*64)*16384 + (size_t)X*128;
  for (int t = tid; t < 1024; t += 256) {
    const int vl = t & 63, nb = (t >> 6) & 3, kb = t >> 8;
    const int c = nb*16 + (vl & 15), j0 = kb*32 + ((vl >> 4) << 3);
    Vl[t] = *(const uint4*)(vsrc + vbase + (size_t)c*16384 + j0);
  }
  __syncthreads();

  float* lOut = dir ? lRow : lCol;
  short8 af[2][4];
  #pragma unroll
  for (int ib2 = 0; ib2 < 2; ++ib2) {
    const int ib = w4*2 + ib2;
    const int m = ib*16 + (lane & 15);
    const size_t pix = (b4h + (dir ? X : m))*128 + (dir ? m : X);
    float qv[8]; up8(*(const uint4*)(q + pix*8), qv);
    float lsum = 0.0f;
    #pragma unroll
    for (int kb = 0; kb < 4; ++kb) {
      const int jbase = kb*32 + ((lane >> 4) << 3);
      union { unsigned short u[8]; short8 s; } pk;
      #pragma unroll
      for (int jj = 0; jj < 8; ++jj) {
        const int j = jbase + jj;
        float p = 0.0f;
        if (dir || (j != m)) p = __expf(dot8(qv, Ks[j]));
        lsum += p;
        pk.u[jj] = f2b(p);
      }
      af[ib2][kb] = pk.s;
    }
    lsum += __shfl_xor(lsum, 16);
    lsum += __shfl_xor(lsum, 32);
    if (lane < 16) lOut[((size_t)z*128 + X)*128 + ib*16 + lane] = lsum;
  }

  f32x4 acc[2][4];
  #pragma unroll
  for (int i2 = 0; i2 < 2; ++i2)
    #pragma unroll
    for (int nb = 0; nb < 4; ++nb) acc[i2][nb] = (f32x4){0.f, 0.f, 0.f, 0.f};
  #pragma unroll
  for (int nb = 0; nb < 4; ++nb)
    #pragma unroll
    for (int kb = 0; kb < 4; ++kb) {
      const short8 bfr = *(short8*)&Vl[(kb*4 + nb)*64 + lane];
      acc[0][nb] = __builtin_amdgcn_mfma_f32_16x16x32_bf16(af[0][kb], bfr, acc[0][nb], 0, 0, 0);
      acc[1][nb] = __builtin_amdgcn_mfma_f32_16x16x32_bf16(af[1][kb], bfr, acc[1][nb], 0, 0, 0);
    }
  __syncthreads();

  #pragma unroll
  for (int i2 = 0; i2 < 2; ++i2)
    #pragma unroll
    for (int nb = 0; nb < 4; ++nb)
      #pragma unroll
      for (int r = 0; r < 4; ++r) {
        const int mm = (w4*2 + i2)*16 + ((lane >> 4) << 2) + r;
        const int cc = nb*16 + (lane & 15);
        Dst[cc*133 + mm] = acc[i2][nb][r];
      }
  __syncthreads();
  float* dst = dir ? outBrF : oColF;
  for (int t = tid; t < 8192; t += 256) {
    const int cc = t >> 7, mm = t & 127;
    dst[vbase + (size_t)cc*16384 + mm] = Dst[cc*133 + mm];
  }
}

// ---------------------------------------------------------------------------
// 4) combine + normalize (vectorized): out[z][c][h][w] =
//    (outBrU[z][c][h][w] + oColU[z][c][w][h]) / (lRow[z][h][w] + lCol[z][w][h])
//    Grid (tile16, z8, cg8): 8 channels per block, float4 I/O.
// ---------------------------------------------------------------------------
__global__ __launch_bounds__(256) void combine_kernel(
    const float* __restrict__ oColU, const float* __restrict__ lRow,
    const float* __restrict__ lCol, float* __restrict__ outBr)
{
  const int tile = blockIdx.x, z = blockIdx.y, cg = blockIdx.z;
  const int h0 = (tile & 3) * 32, w0 = (tile >> 2) * 32, c0 = cg*8;
  const int tid = threadIdx.x;
  __shared__ float Tl[32][33];            // lCol tile [w][h]
  __shared__ __align__(16) float inv[32][36];   // [h][w]
  __shared__ __align__(16) float T4[4][32][36]; // oCol staging [ch][w][h]
  const size_t lzb = (size_t)z * 16384;
  {
    const int w = tid >> 3, h4 = (tid & 7)*4;
    const float4 vc = *(const float4*)(lCol + lzb + (size_t)(w0 + w)*128 + h0 + h4);
    Tl[w][h4+0] = vc.x; Tl[w][h4+1] = vc.y; Tl[w][h4+2] = vc.z; Tl[w][h4+3] = vc.w;
  }
  __syncthreads();
  {
    const int h = tid >> 3, w4 = (tid & 7)*4;
    const float4 lr = *(const float4*)(lRow + lzb + (size_t)(h0 + h)*128 + w0 + w4);
    float4 iv;
    iv.x = 1.0f / (lr.x + Tl[w4+0][h]);
    iv.y = 1.0f / (lr.y + Tl[w4+1][h]);
    iv.z = 1.0f / (lr.z + Tl[w4+2][h]);
    iv.w = 1.0f / (lr.w + Tl[w4+3][h]);
    *(float4*)&inv[h][w4] = iv;
  }
  __syncthreads();
  #pragma unroll
  for (int half = 0; half < 2; ++half) {
    for (int t = tid; t < 1024; t += 256) {
      const int ch = t >> 8, rem = t & 255, w = rem >> 3, h4 = (rem & 7)*4;
      const int c = c0 + half*4 + ch;
      const float4 vc = *(const float4*)(oColU + ((size_t)(z*64 + c))*16384
                                         + (size_t)(w0 + w)*128 + h0 + h4);
      *(float4*)&T4[ch][w][h4] = vc;
    }
    __syncthreads();
    for (int t = tid; t < 1024; t += 256) {
      const int ch = t >> 8, rem = t & 255, h = rem >> 3, w4 = (rem & 7)*4;
      const int c = c0 + half*4 + ch;
      const size_t off = ((size_t)(z*64 + c))*16384 + (size_t)(h0 + h)*128 + w0 + w4;
      float4 o = *(const float4*)(outBr + off);
      const float4 iv = *(const float4*)&inv[h][w4];
      o.x = (o.x + T4[ch][w4+0][h]) * iv.x;
      o.y = (o.y + T4[ch][w4+1][h]) * iv.y;
      o.z = (o.z + T4[ch][w4+2][h]) * iv.z;
      o.w = (o.w + T4[ch][w4+3][h]) * iv.w;
      *(float4*)(outBr + off) = o;
    }
    __syncthreads();
  }
}

// ---------------------------------------------------------------------------
// 5) diff -> 1x1 conv -> fast-erf GELU -> p (fp32), BN partials to global.
// ---------------------------------------------------------------------------
__global__ __launch_bounds__(256) void proj_kernel(
    const float* __restrict__ outA, const float* __restrict__ outB,
    const unsigned short* __restrict__ wp, const unsigned short* __restrict__ bp,
    float* __restrict__ pbuf, float* __restrict__ part)
{
  const int h = blockIdx.x, b = blockIdx.y, wh = blockIdx.z, tid = threadIdx.x;
  const int blk = ((h*4 + b)*2 + wh);   // 0..1023
  __shared__ __align__(16) float diffs[64][64];
  for (int idx = tid; idx < 4096; idx += 256) {
    const int c = idx >> 6, w = idx & 63;
    const size_t off = ((size_t)(b*64 + c)*128 + h)*128 + wh*64 + w;
    diffs[c][w] = fabsf(outA[off] - outB[off]);
  }
  __syncthreads();
  const int cog = tid >> 5, wl = tid & 31;
  float acc[8][2];
  #pragma unroll
  for (int c8 = 0; c8 < 8; ++c8) { acc[c8][0] = 0.f; acc[c8][1] = 0.f; }
  for (int cb = 0; cb < 8; ++cb) {
    uint4 wrow[8];
    #pragma unroll
    for (int c8 = 0; c8 < 8; ++c8) wrow[c8] = *(const uint4*)&wp[(cog*8 + c8)*64 + cb*8];
    #pragma unroll
    for (int t = 0; t < 8; ++t) {
      const int ci = cb*8 + t;
      const float d0 = diffs[ci][wl], d1 = diffs[ci][wl + 32];
      #pragma unroll
      for (int c8 = 0; c8 < 8; ++c8) {
        const float wf = b2f(((const unsigned short*)&wrow[c8])[t]);
        acc[c8][0] += wf*d0; acc[c8][1] += wf*d1;
      }
    }
  }
  #pragma unroll
  for (int c8 = 0; c8 < 8; ++c8) {
    const int co = cog*8 + c8;
    const float bias = b2f(bp[co]);
    const size_t pb = ((size_t)(b*64 + co)*128 + h)*128 + wh*64;
    float s1 = 0.f, s2 = 0.f;
    #pragma unroll
    for (int t = 0; t < 2; ++t) {
      const float x = acc[c8][t] + bias;
      const float g = 0.5f * x * (1.0f + erf_fast(x * 0.70710678118f));
      pbuf[pb + wl + t*32] = g;
      s1 += g; s2 += g*g;
    }
    #pragma unroll
    for (int off = 16; off >= 1; off >>= 1) { s1 += __shfl_xor(s1, off); s2 += __shfl_xor(s2, off); }
    if (wl == 0) {
      part[(size_t)co*1024 + blk] = s1;
      part[(size_t)(64 + co)*1024 + blk] = s2;
    }
  }
}

// ---------------------------------------------------------------------------
// 5b) reduce per-block BN partials: bnAcc[stat] = sum_i part[stat][i]
// ---------------------------------------------------------------------------
__global__ __launch_bounds__(256) void reduce_kernel(
    const float* __restrict__ part, float* __restrict__ bnAcc)
{
  const int stat = blockIdx.x, tid = threadIdx.x;
  const float4 v = *(const float4*)(part + (size_t)stat*1024 + tid*4);
  float s = v.x + v.y + v.z + v.w;
  #pragma unroll
  for (int off = 32; off >= 1; off >>= 1) s += __shfl_xor(s, off);
  __shared__ float ws4[4];
  if ((tid & 63) == 0) ws4[tid >> 6] = s;
  __syncthreads();
  if (tid == 0) bnAcc[stat] = ws4[0] + ws4[1] + ws4[2] + ws4[3];
}

// ---------------------------------------------------------------------------
// 6) BN finalize + residuals, 4 elems/thread, dtype-adaptive I/O
// ---------------------------------------------------------------------------
__global__ __launch_bounds__(256) void final_kernel(
    const float* __restrict__ pbuf, const float* __restrict__ outA, const float* __restrict__ outB,
    const void* __restrict__ x1v, const void* __restrict__ x2v, const int* __restrict__ flag,
    const unsigned short* __restrict__ gA, const unsigned short* __restrict__ gB,
    const unsigned short* __restrict__ bng, const unsigned short* __restrict__ bnb,
    const float* __restrict__ bnAcc, void* __restrict__ outv)
{
  const int f32m = *flag;
  const int idx = (blockIdx.x * 256 + threadIdx.x) * 4;
  const int c = (idx >> 14) & 63;
  const float invN = 1.0f / 65536.0f;
  const float s1 = bnAcc[c], s2 = bnAcc[64 + c];
  const float mean = s1 * invN;
  const float var = s2 * invN - mean*mean;
  const float scale = rsqrtf(var + 1e-5f) * b2f(bng[c]);
  const float beta = b2f(bnb[c]);
  const float ga = b2f(gA[0]), gb = b2f(gB[0]);
  const float4 p4 = *(const float4*)(pbuf + idx);
  const float4 a4 = *(const float4*)(outA + idx);
  const float4 b4 = *(const float4*)(outB + idx);
  float p[4] = {p4.x, p4.y, p4.z, p4.w};
  float a[4] = {a4.x, a4.y, a4.z, a4.w};
  float bb[4] = {b4.x, b4.y, b4.z, b4.w};
  float xa[4], xb[4];
  if (f32m) {
    const float4 t1 = *(const float4*)((const float*)x1v + idx);
    const float4 t2 = *(const float4*)((const float*)x2v + idx);
    xa[0]=t1.x; xa[1]=t1.y; xa[2]=t1.z; xa[3]=t1.w;
    xb[0]=t2.x; xb[1]=t2.y; xb[2]=t2.z; xb[3]=t2.w;
  } else {
    const uint2 x1u = *(const uint2*)((const unsigned short*)x1v + idx);
    const uint2 x2u = *(const uint2*)((const unsigned short*)x2v + idx);
    xa[0] = b2f((unsigned short)(x1u.x & 0xffff)); xa[1] = b2f((unsigned short)(x1u.x >> 16));
    xa[2] = b2f((unsigned short)(x1u.y & 0xffff)); xa[3] = b2f((unsigned short)(x1u.y >> 16));
    xb[0] = b2f((unsigned short)(x2u.x & 0xffff)); xb[1] = b2f((unsigned short)(x2u.x >> 16));
    xb[2] = b2f((unsigned short)(x2u.y & 0xffff)); xb[3] = b2f((unsigned short)(x2u.y >> 16));
  }
  float o1f[4], o2f[4];
  #pragma unroll
  for (int t = 0; t < 4; ++t) {
    const float nv = (p[t] - mean)*scale + beta;
    o1f[t] = ga*a[t] + xa[t] + nv;
    o2f[t] = gb*bb[t] + xb[t] + nv;
  }
  if (f32m) {
    float* of = (float*)outv;
    *(float4*)(of + idx)      = (float4){o1f[0], o1f[1], o1f[2], o1f[3]};
    *(float4*)(of + NE + idx) = (float4){o2f[0], o2f[1], o2f[2], o2f[3]};
  } else {
    unsigned short* oh = (unsigned short*)outv;
    uint2 u1, u2;
    u1.x = (unsigned int)f2b(o1f[0]) | ((unsigned int)f2b(o1f[1]) << 16);
    u1.y = (unsigned int)f2b(o1f[2]) | ((unsigned int)f2b(o1f[3]) << 16);
    u2.x = (unsigned int)f2b(o2f[0]) | ((unsigned int)f2b(o2f[1]) << 16);
    u2.y = (unsigned int)f2b(o2f[2]) | ((unsigned int)f2b(o2f[3]) << 16);
    *(uint2*)(oh + idx) = u1;
    *(uint2*)(oh + NE + idx) = u2;
  }
}

// ---------------------------------------------------------------------------
extern "C" void kernel_launch(void* const* d_in, const int* in_sizes, int n_in,
                              void* d_out, int out_size, void* d_ws, size_t ws_size,
                              hipStream_t stream)
{
  const void* x1  = d_in[0];
  const void* x2  = d_in[1];

  char* ws = (char*)d_ws;
  const size_t MB = 1048576ull;
  unsigned short* q     = (unsigned short*)(ws);                 // 2 MB   [z][pix][8] bf16
  unsigned short* kk    = (unsigned short*)(ws + 2*MB);          // 2 MB
  float* lRow           = (float*)(ws + 4*MB);                   // 512 KB [z][h][w]
  float* lCol           = (float*)(ws + 4*MB + 512*1024);        // 512 KB [z][w][h]
  unsigned short* vStd  = (unsigned short*)(ws + 6*MB);          // 16 MB  [z][C][H][W] bf16
  unsigned short* vT    = (unsigned short*)(ws + 22*MB);         // 16 MB  [z][C][W][H] bf16
  float* outBr          = (float*)(ws + 38*MB);                  // 32 MB  [z][C][H][W] f32
  float* oColF          = (float*)(ws + 70*MB);                  // 32 MB  [z][C][W][H] f32
  float* pbuf           = (float*)(ws + 70*MB);                  // 16 MB, aliases oColF
  float* part           = (float*)(ws + 86*MB);                  // 512 KB, aliases upper oColF
  float* bnAcc          = (float*)(ws + 102*MB);                 // 512 B
  int*   flag           = (int*)(ws + 102*MB + 512);             // 4 B
  unsigned short* wC    = (unsigned short*)(ws + 102*MB + 1024); // canonical params + wqkv + bias

  prelude_kernel<<<64, 256, 0, stream>>>(
      x1, d_in[2], d_in[3], d_in[4], d_in[5], d_in[6], d_in[7], d_in[8], d_in[9],
      d_in[10], d_in[11], d_in[12], d_in[13], d_in[16], d_in[17], d_in[14], d_in[15],
      d_in[18], d_in[19], flag, wC);
  qkv_kernel<<<dim3(64, 4), 256, 0, stream>>>(
      x1, x2, flag, wC + 14696, (const float*)(wC + 25960), q, kk, vStd);
  transpose_v<<<dim3(16, 64, 8), 256, 0, stream>>>(vStd, vT);
  pv_kernel<<<dim3(128, 4, 4), 256, 0, stream>>>(q, kk, vStd, vT, outBr, oColF, lRow, lCol);
  combine_kernel<<<dim3(16, 8, 8), 256, 0, stream>>>(oColF, lRow, lCol, outBr);
  proj_kernel<<<dim3(128, 4, 2), 256, 0, stream>>>(outBr, outBr + NE, wC + 10400, wC + 14496, pbuf, part);
  reduce_kernel<<<128, 256, 0, stream>>>(part, bnAcc);
  final_kernel<<<4096, 256, 0, stream>>>(pbuf, outBr, outBr + NE, x1, x2, flag,
                                         wC + 14560, wC + 14561, wC + 14562, wC + 14626,
                                         bnAcc, d_out);
}

// Round 7
// 234.670 us; speedup vs baseline: 1.7971x; 1.0371x over previous
//
#include <hip/hip_runtime.h>

// CrissCrossAttention on MI355X. Input dtype (fp32 vs bf16) detected at
// runtime; internal compute fp32 with bf16 MFMA operands.
// B=4, C=64, CQ=8, H=W=128.
//
// R7: pv phase-1 scores now computed via MFMA (K=8 zero-padded to 32),
// killing the dot8 VALU loop and the 4-way-conflicted Ks reads
// (SQ_LDS_BANK_CONFLICT was 524288/dispatch). P round-trips through LDS
// (C-layout -> bf16 [128][132] -> A-frag reads).

#define NE 4194304ull   // B*C*H*W elements per image tensor

typedef __attribute__((ext_vector_type(8))) short short8;
typedef __attribute__((ext_vector_type(4))) float f32x4;

#define HD __device__ __forceinline__

HD float b2f(unsigned short u) { union { unsigned int i; float f; } v; v.i = ((unsigned int)u) << 16; return v.f; }
HD unsigned short f2b(float x) {
  union { float f; unsigned int i; } v; v.f = x;
  unsigned int r = v.i + 0x7FFFu + ((v.i >> 16) & 1u);
  return (unsigned short)(r >> 16);
}

// Abramowitz-Stegun 7.1.26 erf approximation, |abs err| <= 1.5e-7.
HD float erf_fast(float x) {
  const float ax = fabsf(x);
  const float t = 1.0f / (1.0f + 0.3275911f * ax);
  const float poly = ((((1.061405429f*t - 1.453152027f)*t + 1.421413741f)*t
                       - 0.284496736f)*t + 0.254829592f)*t;
  const float y = 1.0f - poly * __expf(-ax*ax);
  return copysignf(y, x);
}

// read element i of src as bf16, canonicalizing from fp32 if f!=0
HD unsigned short ldbf(const void* s0, int i, int f) {
  return f ? f2b(((const float*)s0)[i]) : ((const unsigned short*)s0)[i];
}

// ---------------------------------------------------------------------------
// 0) Prelude (64 blocks): detect dtype (redundantly per block), canonicalize
//    params to bf16 wout, build wqkv[11][16][64] bf16 + wbias[11][16] f32
//    directly from sources. Mtiles: 0=qA | 1=kA,qB | 2=kB | 3-6=vA | 7-10=vB.
// ---------------------------------------------------------------------------
__global__ __launch_bounds__(256) void prelude_kernel(
    const void* x1,
    const void* wqA, const void* bqA, const void* wkA, const void* bkA,
    const void* wvA, const void* bvA, const void* wqB, const void* bqB,
    const void* wkB, const void* bkB, const void* wvB, const void* bvB,
    const void* wp, const void* bp, const void* gA, const void* gB,
    const void* bng, const void* bnb,
    int* flag, unsigned short* wout)
{
  __shared__ int s;
  if (threadIdx.x == 0) s = 0;
  __syncthreads();
  const float a = fabsf(b2f(((const unsigned short*)x1)[threadIdx.x]));
  if (a > 1000.0f) atomicOr(&s, 1);
  __syncthreads();
  const int f = s;
  if (blockIdx.x == 0 && threadIdx.x == 0) *flag = f;

  const void* srcs[18] = {wqA,bqA,wkA,bkA,wvA,bvA,wqB,bqB,wkB,bkB,wvB,bvB,wp,bp,gA,gB,bng,bnb};
  const int   ns[18]   = {512,  8,512,  8,4096, 64,512,  8,512,  8,4096, 64,4096,64, 1, 1, 64, 64};
  unsigned short* wqkv = wout + 14696;
  float* wbias = (float*)(wout + 25960);

  const int gstride = gridDim.x * 256;
  for (int idx = blockIdx.x*256 + threadIdx.x; idx < 26136; idx += gstride) {
    if (idx < 14690) {
      int off = idx, k2 = 0;
      while (off >= ns[k2]) { off -= ns[k2]; ++k2; }
      wout[idx] = ldbf(srcs[k2], off, f);
    } else if (idx >= 25960) {
      const int i3 = idx - 25960, mt = i3 >> 4, r = i3 & 15;
      float val = 0.0f;
      if (mt == 0)      { if (r < 8) val = b2f(ldbf(bqA, r, f)); }
      else if (mt == 1) { val = b2f((r < 8) ? ldbf(bkA, r, f) : ldbf(bqB, r - 8, f)); }
      else if (mt == 2) { if (r < 8) val = b2f(ldbf(bkB, r, f)); }
      else if (mt < 7)  { val = b2f(ldbf(bvA, (mt-3)*16 + r, f)); }
      else              { val = b2f(ldbf(bvB, (mt-7)*16 + r, f)); }
      wbias[i3] = val;
    } else if (idx >= 14696) {
      const int i2 = idx - 14696;
      const int mt = i2 >> 10, rem = i2 & 1023, r = rem >> 6, ci = rem & 63;
      unsigned short val = 0;
      if (mt == 0)      { if (r < 8) val = ldbf(wqA, r*64 + ci, f); }
      else if (mt == 1) { val = (r < 8) ? ldbf(wkA, r*64 + ci, f) : ldbf(wqB, (r-8)*64 + ci, f); }
      else if (mt == 2) { if (r < 8) val = ldbf(wkB, r*64 + ci, f); }
      else if (mt < 7)  { val = ldbf(wvA, ((mt-3)*16 + r)*64 + ci, f); }
      else              { val = ldbf(wvB, ((mt-7)*16 + r)*64 + ci, f); }
      wqkv[i2] = val;
    }
  }
}

// ---------------------------------------------------------------------------
// 1) QKV via MFMA. Grid (hp=64, b=4). Per block: 256 pixels (2 h-rows),
//    D[row][pix] = W x X. X staged pixel-major in LDS (pad 66), B-frags
//    cached in registers (x1 pass then x2 pass reusing the same LDS), then
//    11 mtiles of 8 MFMAs each with double-buffered LDS epilogue.
// ---------------------------------------------------------------------------
__global__ __launch_bounds__(256) void qkv_kernel(
    const void* __restrict__ x1v, const void* __restrict__ x2v, const int* __restrict__ flag,
    const unsigned short* __restrict__ wqkv, const float* __restrict__ wbias,
    unsigned short* __restrict__ q, unsigned short* __restrict__ k,
    unsigned short* __restrict__ v)
{
  const int hp = blockIdx.x, b = blockIdx.y;
  const int h0 = hp*2;
  const int tid = threadIdx.x, lane = tid & 63, w4 = tid >> 6;
  const int col = lane & 15, quad = lane >> 4;
  const int f32m = *flag;
  __shared__ __align__(16) char smem[33792];   // Xb[256][66] bf16, later S0/S1
  unsigned short* Xb = (unsigned short*)smem;
  unsigned short* S0 = (unsigned short*)smem;          // 16x264 bf16 = 8448B
  unsigned short* S1 = (unsigned short*)(smem + 8448);
  const size_t gb = (size_t)b*1048576 + (size_t)h0*128;

  short8 Bc[2][8];   // [pass: 0=x1, 1=x2][ntile*2 + kstep]
  #pragma unroll
  for (int pass = 0; pass < 2; ++pass) {
    const void* xv = pass ? x2v : x1v;
    for (int t = tid; t < 2048; t += 256) {
      const int c = t >> 5, rem = t & 31, hh = rem >> 4, w8 = (rem & 15)*8;
      const int n = hh*128 + w8;
      const size_t a = gb + (size_t)c*16384 + (size_t)hh*128 + w8;
      unsigned short vals[8];
      if (f32m) {
        const float* xf = (const float*)xv;
        const float4 f0 = *(const float4*)(xf + a);
        const float4 f1 = *(const float4*)(xf + a + 4);
        vals[0]=f2b(f0.x); vals[1]=f2b(f0.y); vals[2]=f2b(f0.z); vals[3]=f2b(f0.w);
        vals[4]=f2b(f1.x); vals[5]=f2b(f1.y); vals[6]=f2b(f1.z); vals[7]=f2b(f1.w);
      } else {
        const uint4 u = *(const uint4*)((const unsigned short*)xv + a);
        vals[0]=(unsigned short)(u.x & 0xffff); vals[1]=(unsigned short)(u.x >> 16);
        vals[2]=(unsigned short)(u.y & 0xffff); vals[3]=(unsigned short)(u.y >> 16);
        vals[4]=(unsigned short)(u.z & 0xffff); vals[5]=(unsigned short)(u.z >> 16);
        vals[6]=(unsigned short)(u.w & 0xffff); vals[7]=(unsigned short)(u.w >> 16);
      }
      #pragma unroll
      for (int i = 0; i < 8; ++i) Xb[(n + i)*66 + c] = vals[i];
    }
    __syncthreads();
    const unsigned int* U = (const unsigned int*)Xb;
    #pragma unroll
    for (int nt = 0; nt < 4; ++nt)
      #pragma unroll
      for (int ks = 0; ks < 2; ++ks) {
        const int n = w4*64 + nt*16 + col;
        const int base = n*33 + (ks*32 + quad*8)/2;
        union { unsigned int u32[4]; short8 s; } p;
        #pragma unroll
        for (int jj = 0; jj < 4; ++jj) p.u32[jj] = U[base + jj];
        Bc[pass][nt*2 + ks] = p.s;
      }
    __syncthreads();
  }

  #pragma unroll
  for (int mt = 0; mt < 11; ++mt) {
    f32x4 acc[4];
    #pragma unroll
    for (int nt = 0; nt < 4; ++nt) acc[nt] = (f32x4){0.f, 0.f, 0.f, 0.f};
    #pragma unroll
    for (int ks = 0; ks < 2; ++ks) {
      union { uint4 u; short8 s; } A;
      A.u = *(const uint4*)(wqkv + mt*1024 + col*64 + ks*32 + quad*8);
      #pragma unroll
      for (int nt = 0; nt < 4; ++nt)
        acc[nt] = __builtin_amdgcn_mfma_f32_16x16x32_bf16(
            A.s, (mt == 0) ? Bc[1][nt*2 + ks] : Bc[0][nt*2 + ks], acc[nt], 0, 0, 0);
    }
    float bias[4];
    #pragma unroll
    for (int r = 0; r < 4; ++r) bias[r] = wbias[mt*16 + quad*4 + r];
    unsigned short* S = (mt & 1) ? S1 : S0;
    #pragma unroll
    for (int nt = 0; nt < 4; ++nt)
      #pragma unroll
      for (int r = 0; r < 4; ++r) {
        const int row = quad*4 + r;
        const int nloc = w4*64 + nt*16 + col;
        S[row*264 + nloc] = f2b(acc[nt][r] + bias[r]);
      }
    __syncthreads();
    if (mt < 3) {
      const int nloc = tid;
      const int pixg = h0*128 + nloc;
      union { unsigned short u[8]; uint4 v4; } P;
      #pragma unroll
      for (int r = 0; r < 8; ++r) P.u[r] = S[r*264 + nloc];
      if (mt == 0) {
        *(uint4*)(q + ((size_t)b*16384 + pixg)*8) = P.v4;
      } else if (mt == 1) {
        *(uint4*)(k + ((size_t)b*16384 + pixg)*8) = P.v4;
        #pragma unroll
        for (int r = 0; r < 8; ++r) P.u[r] = S[(8 + r)*264 + nloc];
        *(uint4*)(q + ((size_t)(4 + b)*16384 + pixg)*8) = P.v4;
      } else {
        *(uint4*)(k + ((size_t)(4 + b)*16384 + pixg)*8) = P.v4;
      }
    } else {
      const int vm = (mt >= 7) ? mt - 7 : mt - 3;
      const int z  = (mt >= 7) ? 4 + b : b;
      const int cl = tid >> 4, u = tid & 15;
      const int co = vm*16 + cl;
      const uint4 a0 = *(const uint4*)&S[cl*264 + u*16];
      const uint4 a1 = *(const uint4*)&S[cl*264 + u*16 + 8];
      unsigned short* dst = v + ((size_t)(z*64 + co)*16384 + (size_t)h0*128 + u*16);
      *(uint4*)dst = a0;
      *(uint4*)(dst + 8) = a1;
    }
  }
}

// ---------------------------------------------------------------------------
// 2) v transpose: vT[z][c][w][h] = v[z][c][h][w]   (z = br*4+b)
// ---------------------------------------------------------------------------
__global__ __launch_bounds__(256) void transpose_v(
    const unsigned short* __restrict__ vStd, unsigned short* __restrict__ vT)
{
  const int tile = blockIdx.x, c = blockIdx.y, z = blockIdx.z;
  const int h0 = (tile & 3) * 32, w0 = (tile >> 2) * 32;
  const size_t base = ((size_t)z*64 + c) * 16384;
  __shared__ unsigned short T[32][33];
  const int tid = threadIdx.x;
  for (int idx = tid; idx < 1024; idx += 256) {
    const int r = idx >> 5, cc = idx & 31;
    T[r][cc] = vStd[base + (size_t)(h0 + r)*128 + (w0 + cc)];
  }
  __syncthreads();
  for (int idx = tid; idx < 1024; idx += 256) {
    const int r = idx >> 5, cc = idx & 31;
    vT[base + (size_t)(w0 + r)*128 + (h0 + cc)] = T[cc][r];
  }
}

// ---------------------------------------------------------------------------
// 3) PV, both GEMMs via MFMA. Phase S: S=Q K^T with K-dim 8 zero-padded to 32
//    (quads 1-3 hold zeros). exp(S) (unnormalized, |S|<~4) written bf16 to
//    P[128][132] in LDS; per-pixel l-sums via 4 shuffle reductions. Phase PV:
//    A-frags read back from P, V staged B-frag-swizzled (over dead Ks),
//    32 mfma per wave, transpose epilogue through LDS (over dead P).
// ---------------------------------------------------------------------------
__global__ __launch_bounds__(256) void pv_kernel(
    const unsigned short* __restrict__ q, const unsigned short* __restrict__ k,
    const unsigned short* __restrict__ vStd, const unsigned short* __restrict__ vT,
    float* __restrict__ outBrF, float* __restrict__ oColF,
    float* __restrict__ lRow, float* __restrict__ lCol)
{
  const int X = blockIdx.x, b = blockIdx.y;
  const int br = blockIdx.z & 1, dir = blockIdx.z >> 1;
  const int tid = threadIdx.x, lane = tid & 63, w4 = tid >> 6;
  const int col = lane & 15, quad = lane >> 4;
  const int z = br*4 + b;
  const size_t b4h = (size_t)z * 128;
  __shared__ __align__(16) char smemA[34048];  // P bf16[128][132] -> Dst f32[64][133]
  __shared__ __align__(16) char smemB[16384];  // Ks uint4[128] -> Vl
  unsigned short* P = (unsigned short*)smemA;
  float* Dst = (float*)smemA;
  uint4* Ks = (uint4*)smemB;
  uint4* Vl = (uint4*)smemB;

  // s0: stage K pixels
  if (tid < 128) {
    const int j = tid;
    const size_t pix = (b4h + (dir ? X : j))*128 + (dir ? j : X);
    Ks[j] = *(const uint4*)(k + pix*8);
  }
  __syncthreads();

  // s1: S-tiles via MFMA, exp, P to LDS, l-sums
  const uint4 zero4 = {0u, 0u, 0u, 0u};
  short8 Afr[2];
  #pragma unroll
  for (int ib2 = 0; ib2 < 2; ++ib2) {
    uint4 a = zero4;
    if (quad == 0) {
      const int m = (w4*2 + ib2)*16 + col;
      const size_t pix = (b4h + (dir ? X : m))*128 + (dir ? m : X);
      a = *(const uint4*)(q + pix*8);
    }
    union { uint4 u; short8 s; } cv; cv.u = a; Afr[ib2] = cv.s;
  }
  float lsum[2][4];
  #pragma unroll
  for (int ib2 = 0; ib2 < 2; ++ib2)
    #pragma unroll
    for (int r = 0; r < 4; ++r) lsum[ib2][r] = 0.0f;
  #pragma unroll
  for (int nb = 0; nb < 8; ++nb) {
    uint4 bu = (quad == 0) ? Ks[nb*16 + col] : zero4;
    union { uint4 u; short8 s; } bv; bv.u = bu;
    f32x4 sA = __builtin_amdgcn_mfma_f32_16x16x32_bf16(Afr[0], bv.s, (f32x4){0.f,0.f,0.f,0.f}, 0, 0, 0);
    f32x4 sB = __builtin_amdgcn_mfma_f32_16x16x32_bf16(Afr[1], bv.s, (f32x4){0.f,0.f,0.f,0.f}, 0, 0, 0);
    const int j = nb*16 + col;
    #pragma unroll
    for (int ib2 = 0; ib2 < 2; ++ib2) {
      const int mbase = (w4*2 + ib2)*16 + quad*4;
      #pragma unroll
      for (int r = 0; r < 4; ++r) {
        const int m = mbase + r;
        const float sv = ib2 ? sB[r] : sA[r];
        float p = 0.0f;
        if (dir || (j != m)) p = __expf(sv);
        lsum[ib2][r] += p;
        P[m*132 + j] = f2b(p);
      }
    }
  }
  #pragma unroll
  for (int ib2 = 0; ib2 < 2; ++ib2)
    #pragma unroll
    for (int r = 0; r < 4; ++r) {
      float s = lsum[ib2][r];
      s += __shfl_xor(s, 1); s += __shfl_xor(s, 2);
      s += __shfl_xor(s, 4); s += __shfl_xor(s, 8);
      if (col == 0) {
        const int m = (w4*2 + ib2)*16 + quad*4 + r;
        float* lOut = dir ? lRow : lCol;
        lOut[((size_t)z*128 + X)*128 + m] = s;
      }
    }
  __syncthreads();

  // s2: A-frags from P; stage Vl over dead Ks
  short8 af[2][4];
  #pragma unroll
  for (int ib2 = 0; ib2 < 2; ++ib2) {
    const int m = (w4*2 + ib2)*16 + col;
    #pragma unroll
    for (int kb = 0; kb < 4; ++kb) {
      const int j0 = kb*32 + quad*8;
      union { uint2 u[2]; short8 s; } pk;
      pk.u[0] = *(const uint2*)&P[m*132 + j0];
      pk.u[1] = *(const uint2*)&P[m*132 + j0 + 4];
      af[ib2][kb] = pk.s;
    }
  }
  const unsigned short* vsrc = dir ? vStd : vT;
  const size_t vbase = ((size_t)z*64)*16384 + (size_t)X*128;
  for (int t = tid; t < 1024; t += 256) {
    const int vl = t & 63, nb = (t >> 6) & 3, kb = t >> 8;
    const int c = nb*16 + (vl & 15), j0 = kb*32 + ((vl >> 4) << 3);
    Vl[t] = *(const uint4*)(vsrc + vbase + (size_t)c*16384 + j0);
  }
  __syncthreads();

  // s3: D(128m x 64c) = P * V
  f32x4 acc[2][4];
  #pragma unroll
  for (int i2 = 0; i2 < 2; ++i2)
    #pragma unroll
    for (int nb = 0; nb < 4; ++nb) acc[i2][nb] = (f32x4){0.f, 0.f, 0.f, 0.f};
  #pragma unroll
  for (int nb = 0; nb < 4; ++nb)
    #pragma unroll
    for (int kb = 0; kb < 4; ++kb) {
      const short8 bfr = *(short8*)&Vl[(kb*4 + nb)*64 + lane];
      acc[0][nb] = __builtin_amdgcn_mfma_f32_16x16x32_bf16(af[0][kb], bfr, acc[0][nb], 0, 0, 0);
      acc[1][nb] = __builtin_amdgcn_mfma_f32_16x16x32_bf16(af[1][kb], bfr, acc[1][nb], 0, 0, 0);
    }
  __syncthreads();

  // s4: transpose epilogue through LDS (over dead P), coalesced fp32 stores
  #pragma unroll
  for (int i2 = 0; i2 < 2; ++i2)
    #pragma unroll
    for (int nb = 0; nb < 4; ++nb)
      #pragma unroll
      for (int r = 0; r < 4; ++r) {
        const int mm = (w4*2 + i2)*16 + ((lane >> 4) << 2) + r;
        const int cc = nb*16 + (lane & 15);
        Dst[cc*133 + mm] = acc[i2][nb][r];
      }
  __syncthreads();
  float* dst = dir ? outBrF : oColF;
  for (int t = tid; t < 8192; t += 256) {
    const int cc = t >> 7, mm = t & 127;
    dst[vbase + (size_t)cc*16384 + mm] = Dst[cc*133 + mm];
  }
}

// ---------------------------------------------------------------------------
// 4) combine + normalize (vectorized): out[z][c][h][w] =
//    (outBrU[z][c][h][w] + oColU[z][c][w][h]) / (lRow[z][h][w] + lCol[z][w][h])
//    Grid (tile16, z8, cg8): 8 channels per block, float4 I/O.
// ---------------------------------------------------------------------------
__global__ __launch_bounds__(256) void combine_kernel(
    const float* __restrict__ oColU, const float* __restrict__ lRow,
    const float* __restrict__ lCol, float* __restrict__ outBr)
{
  const int tile = blockIdx.x, z = blockIdx.y, cg = blockIdx.z;
  const int h0 = (tile & 3) * 32, w0 = (tile >> 2) * 32, c0 = cg*8;
  const int tid = threadIdx.x;
  __shared__ float Tl[32][33];            // lCol tile [w][h]
  __shared__ __align__(16) float inv[32][36];   // [h][w]
  __shared__ __align__(16) float T4[4][32][36]; // oCol staging [ch][w][h]
  const size_t lzb = (size_t)z * 16384;
  {
    const int w = tid >> 3, h4 = (tid & 7)*4;
    const float4 vc = *(const float4*)(lCol + lzb + (size_t)(w0 + w)*128 + h0 + h4);
    Tl[w][h4+0] = vc.x; Tl[w][h4+1] = vc.y; Tl[w][h4+2] = vc.z; Tl[w][h4+3] = vc.w;
  }
  __syncthreads();
  {
    const int h = tid >> 3, w4 = (tid & 7)*4;
    const float4 lr = *(const float4*)(lRow + lzb + (size_t)(h0 + h)*128 + w0 + w4);
    float4 iv;
    iv.x = 1.0f / (lr.x + Tl[w4+0][h]);
    iv.y = 1.0f / (lr.y + Tl[w4+1][h]);
    iv.z = 1.0f / (lr.z + Tl[w4+2][h]);
    iv.w = 1.0f / (lr.w + Tl[w4+3][h]);
    *(float4*)&inv[h][w4] = iv;
  }
  __syncthreads();
  #pragma unroll
  for (int half = 0; half < 2; ++half) {
    for (int t = tid; t < 1024; t += 256) {
      const int ch = t >> 8, rem = t & 255, w = rem >> 3, h4 = (rem & 7)*4;
      const int c = c0 + half*4 + ch;
      const float4 vc = *(const float4*)(oColU + ((size_t)(z*64 + c))*16384
                                         + (size_t)(w0 + w)*128 + h0 + h4);
      *(float4*)&T4[ch][w][h4] = vc;
    }
    __syncthreads();
    for (int t = tid; t < 1024; t += 256) {
      const int ch = t >> 8, rem = t & 255, h = rem >> 3, w4 = (rem & 7)*4;
      const int c = c0 + half*4 + ch;
      const size_t off = ((size_t)(z*64 + c))*16384 + (size_t)(h0 + h)*128 + w0 + w4;
      float4 o = *(const float4*)(outBr + off);
      const float4 iv = *(const float4*)&inv[h][w4];
      o.x = (o.x + T4[ch][w4+0][h]) * iv.x;
      o.y = (o.y + T4[ch][w4+1][h]) * iv.y;
      o.z = (o.z + T4[ch][w4+2][h]) * iv.z;
      o.w = (o.w + T4[ch][w4+3][h]) * iv.w;
      *(float4*)(outBr + off) = o;
    }
    __syncthreads();
  }
}

// ---------------------------------------------------------------------------
// 5) diff -> 1x1 conv -> fast-erf GELU -> p (fp32), BN partials to global.
// ---------------------------------------------------------------------------
__global__ __launch_bounds__(256) void proj_kernel(
    const float* __restrict__ outA, const float* __restrict__ outB,
    const unsigned short* __restrict__ wp, const unsigned short* __restrict__ bp,
    float* __restrict__ pbuf, float* __restrict__ part)
{
  const int h = blockIdx.x, b = blockIdx.y, wh = blockIdx.z, tid = threadIdx.x;
  const int blk = ((h*4 + b)*2 + wh);   // 0..1023
  __shared__ __align__(16) float diffs[64][64];
  for (int idx = tid; idx < 4096; idx += 256) {
    const int c = idx >> 6, w = idx & 63;
    const size_t off = ((size_t)(b*64 + c)*128 + h)*128 + wh*64 + w;
    diffs[c][w] = fabsf(outA[off] - outB[off]);
  }
  __syncthreads();
  const int cog = tid >> 5, wl = tid & 31;
  float acc[8][2];
  #pragma unroll
  for (int c8 = 0; c8 < 8; ++c8) { acc[c8][0] = 0.f; acc[c8][1] = 0.f; }
  for (int cb = 0; cb < 8; ++cb) {
    uint4 wrow[8];
    #pragma unroll
    for (int c8 = 0; c8 < 8; ++c8) wrow[c8] = *(const uint4*)&wp[(cog*8 + c8)*64 + cb*8];
    #pragma unroll
    for (int t = 0; t < 8; ++t) {
      const int ci = cb*8 + t;
      const float d0 = diffs[ci][wl], d1 = diffs[ci][wl + 32];
      #pragma unroll
      for (int c8 = 0; c8 < 8; ++c8) {
        const float wf = b2f(((const unsigned short*)&wrow[c8])[t]);
        acc[c8][0] += wf*d0; acc[c8][1] += wf*d1;
      }
    }
  }
  #pragma unroll
  for (int c8 = 0; c8 < 8; ++c8) {
    const int co = cog*8 + c8;
    const float bias = b2f(bp[co]);
    const size_t pb = ((size_t)(b*64 + co)*128 + h)*128 + wh*64;
    float s1 = 0.f, s2 = 0.f;
    #pragma unroll
    for (int t = 0; t < 2; ++t) {
      const float x = acc[c8][t] + bias;
      const float g = 0.5f * x * (1.0f + erf_fast(x * 0.70710678118f));
      pbuf[pb + wl + t*32] = g;
      s1 += g; s2 += g*g;
    }
    #pragma unroll
    for (int off = 16; off >= 1; off >>= 1) { s1 += __shfl_xor(s1, off); s2 += __shfl_xor(s2, off); }
    if (wl == 0) {
      part[(size_t)co*1024 + blk] = s1;
      part[(size_t)(64 + co)*1024 + blk] = s2;
    }
  }
}

// ---------------------------------------------------------------------------
// 5b) reduce per-block BN partials: bnAcc[stat] = sum_i part[stat][i]
// ---------------------------------------------------------------------------
__global__ __launch_bounds__(256) void reduce_kernel(
    const float* __restrict__ part, float* __restrict__ bnAcc)
{
  const int stat = blockIdx.x, tid = threadIdx.x;
  const float4 v = *(const float4*)(part + (size_t)stat*1024 + tid*4);
  float s = v.x + v.y + v.z + v.w;
  #pragma unroll
  for (int off = 32; off >= 1; off >>= 1) s += __shfl_xor(s, off);
  __shared__ float ws4[4];
  if ((tid & 63) == 0) ws4[tid >> 6] = s;
  __syncthreads();
  if (tid == 0) bnAcc[stat] = ws4[0] + ws4[1] + ws4[2] + ws4[3];
}

// ---------------------------------------------------------------------------
// 6) BN finalize + residuals, 4 elems/thread, dtype-adaptive I/O
// ---------------------------------------------------------------------------
__global__ __launch_bounds__(256) void final_kernel(
    const float* __restrict__ pbuf, const float* __restrict__ outA, const float* __restrict__ outB,
    const void* __restrict__ x1v, const void* __restrict__ x2v, const int* __restrict__ flag,
    const unsigned short* __restrict__ gA, const unsigned short* __restrict__ gB,
    const unsigned short* __restrict__ bng, const unsigned short* __restrict__ bnb,
    const float* __restrict__ bnAcc, void* __restrict__ outv)
{
  const int f32m = *flag;
  const int idx = (blockIdx.x * 256 + threadIdx.x) * 4;
  const int c = (idx >> 14) & 63;
  const float invN = 1.0f / 65536.0f;
  const float s1 = bnAcc[c], s2 = bnAcc[64 + c];
  const float mean = s1 * invN;
  const float var = s2 * invN - mean*mean;
  const float scale = rsqrtf(var + 1e-5f) * b2f(bng[c]);
  const float beta = b2f(bnb[c]);
  const float ga = b2f(gA[0]), gb = b2f(gB[0]);
  const float4 p4 = *(const float4*)(pbuf + idx);
  const float4 a4 = *(const float4*)(outA + idx);
  const float4 b4 = *(const float4*)(outB + idx);
  float p[4] = {p4.x, p4.y, p4.z, p4.w};
  float a[4] = {a4.x, a4.y, a4.z, a4.w};
  float bb[4] = {b4.x, b4.y, b4.z, b4.w};
  float xa[4], xb[4];
  if (f32m) {
    const float4 t1 = *(const float4*)((const float*)x1v + idx);
    const float4 t2 = *(const float4*)((const float*)x2v + idx);
    xa[0]=t1.x; xa[1]=t1.y; xa[2]=t1.z; xa[3]=t1.w;
    xb[0]=t2.x; xb[1]=t2.y; xb[2]=t2.z; xb[3]=t2.w;
  } else {
    const uint2 x1u = *(const uint2*)((const unsigned short*)x1v + idx);
    const uint2 x2u = *(const uint2*)((const unsigned short*)x2v + idx);
    xa[0] = b2f((unsigned short)(x1u.x & 0xffff)); xa[1] = b2f((unsigned short)(x1u.x >> 16));
    xa[2] = b2f((unsigned short)(x1u.y & 0xffff)); xa[3] = b2f((unsigned short)(x1u.y >> 16));
    xb[0] = b2f((unsigned short)(x2u.x & 0xffff)); xb[1] = b2f((unsigned short)(x2u.x >> 16));
    xb[2] = b2f((unsigned short)(x2u.y & 0xffff)); xb[3] = b2f((unsigned short)(x2u.y >> 16));
  }
  float o1f[4], o2f[4];
  #pragma unroll
  for (int t = 0; t < 4; ++t) {
    const float nv = (p[t] - mean)*scale + beta;
    o1f[t] = ga*a[t] + xa[t] + nv;
    o2f[t] = gb*bb[t] + xb[t] + nv;
  }
  if (f32m) {
    float* of = (float*)outv;
    *(float4*)(of + idx)      = (float4){o1f[0], o1f[1], o1f[2], o1f[3]};
    *(float4*)(of + NE + idx) = (float4){o2f[0], o2f[1], o2f[2], o2f[3]};
  } else {
    unsigned short* oh = (unsigned short*)outv;
    uint2 u1, u2;
    u1.x = (unsigned int)f2b(o1f[0]) | ((unsigned int)f2b(o1f[1]) << 16);
    u1.y = (unsigned int)f2b(o1f[2]) | ((unsigned int)f2b(o1f[3]) << 16);
    u2.x = (unsigned int)f2b(o2f[0]) | ((unsigned int)f2b(o2f[1]) << 16);
    u2.y = (unsigned int)f2b(o2f[2]) | ((unsigned int)f2b(o2f[3]) << 16);
    *(uint2*)(oh + idx) = u1;
    *(uint2*)(oh + NE + idx) = u2;
  }
}

// ---------------------------------------------------------------------------
extern "C" void kernel_launch(void* const* d_in, const int* in_sizes, int n_in,
                              void* d_out, int out_size, void* d_ws, size_t ws_size,
                              hipStream_t stream)
{
  const void* x1  = d_in[0];
  const void* x2  = d_in[1];

  char* ws = (char*)d_ws;
  const size_t MB = 1048576ull;
  unsigned short* q     = (unsigned short*)(ws);                 // 2 MB   [z][pix][8] bf16
  unsigned short* kk    = (unsigned short*)(ws + 2*MB);          // 2 MB
  float* lRow           = (float*)(ws + 4*MB);                   // 512 KB [z][h][w]
  float* lCol           = (float*)(ws + 4*MB + 512*1024);        // 512 KB [z][w][h]
  unsigned short* vStd  = (unsigned short*)(ws + 6*MB);          // 16 MB  [z][C][H][W] bf16
  unsigned short* vT    = (unsigned short*)(ws + 22*MB);         // 16 MB  [z][C][W][H] bf16
  float* outBr          = (float*)(ws + 38*MB);                  // 32 MB  [z][C][H][W] f32
  float* oColF          = (float*)(ws + 70*MB);                  // 32 MB  [z][C][W][H] f32
  float* pbuf           = (float*)(ws + 70*MB);                  // 16 MB, aliases oColF
  float* part           = (float*)(ws + 86*MB);                  // 512 KB, aliases upper oColF
  float* bnAcc          = (float*)(ws + 102*MB);                 // 512 B
  int*   flag           = (int*)(ws + 102*MB + 512);             // 4 B
  unsigned short* wC    = (unsigned short*)(ws + 102*MB + 1024); // canonical params + wqkv + bias

  prelude_kernel<<<64, 256, 0, stream>>>(
      x1, d_in[2], d_in[3], d_in[4], d_in[5], d_in[6], d_in[7], d_in[8], d_in[9],
      d_in[10], d_in[11], d_in[12], d_in[13], d_in[16], d_in[17], d_in[14], d_in[15],
      d_in[18], d_in[19], flag, wC);
  qkv_kernel<<<dim3(64, 4), 256, 0, stream>>>(
      x1, x2, flag, wC + 14696, (const float*)(wC + 25960), q, kk, vStd);
  transpose_v<<<dim3(16, 64, 8), 256, 0, stream>>>(vStd, vT);
  pv_kernel<<<dim3(128, 4, 4), 256, 0, stream>>>(q, kk, vStd, vT, outBr, oColF, lRow, lCol);
  combine_kernel<<<dim3(16, 8, 8), 256, 0, stream>>>(oColF, lRow, lCol, outBr);
  proj_kernel<<<dim3(128, 4, 2), 256, 0, stream>>>(outBr, outBr + NE, wC + 10400, wC + 14496, pbuf, part);
  reduce_kernel<<<128, 256, 0, stream>>>(part, bnAcc);
  final_kernel<<<4096, 256, 0, stream>>>(pbuf, outBr, outBr + NE, x1, x2, flag,
                                         wC + 14560, wC + 14561, wC + 14562, wC + 14626,
                                         bnAcc, d_out);
}